// Round 14
// baseline (63.051 us; speedup 1.0000x reference)
//
#include <hip/hip_runtime.h>
#include <hip/hip_bf16.h>
#include <math.h>

// Problem constants
#define B_   2
#define S_   2048
#define DM   768
#define H_   16      // N_QK
#define C_   256     // N_OV
#define VKV_ 16
#define SK   2064    // S_ + VKV_
#define SKP  2080
#define NT_  65      // key tiles per bh

#define TSPLIT 16
#define MAXSP  5     // ceil(65/16)
#define NACT   164   // active (qt,sp) pairs per bh

typedef __attribute__((ext_vector_type(8))) short short8;    // 8 bf16
typedef __attribute__((ext_vector_type(4))) short short4v;
typedef __attribute__((ext_vector_type(4))) float f32x4;
typedef __attribute__((ext_vector_type(16))) float f32x16;
typedef __attribute__((ext_vector_type(4))) unsigned uint4v;

// log2(e) / SCALE folded into Q so p = exp2(s)
#define QSCALE 0.360673760222240851f
// log2(10000)/8
#define L2B8   1.6609640474436811f

__device__ __forceinline__ short tobf(float f) {
    union { float f; unsigned u; } x; x.f = f;
    unsigned r = x.u + 0x7FFFu + ((x.u >> 16) & 1u);   // RNE
    return (short)(r >> 16);
}
__device__ __forceinline__ float frombf_lo(unsigned u) {
    union { unsigned u; float f; } x; x.u = u << 16; return x.f;
}
__device__ __forceinline__ float frombf_hi(unsigned u) {
    union { unsigned u; float f; } x; x.u = u & 0xFFFF0000u; return x.f;
}

__device__ __forceinline__ void gload_lds16(const short* g, short* l) {
    __builtin_amdgcn_global_load_lds(
        (const __attribute__((address_space(1))) unsigned int*)g,
        (__attribute__((address_space(3))) unsigned int*)l, 16, 0, 0);
}

// ---------------------------------------------------------------------------
// conv_all: resid->bf16, weights pack, bias pack, K/V tail (s>=2048) init.
// ---------------------------------------------------------------------------
#define NRES (4096*768/4)
#define NWQ  (768*768)
#define NWO  (768*256)
__global__ __launch_bounds__(256) void conv_all(
    const float* __restrict__ resid,
    const float* __restrict__ WQ, const float* __restrict__ WK,
    const float* __restrict__ WV, const float* __restrict__ WO,
    const float* __restrict__ bQ, const float* __restrict__ bK,
    const float* __restrict__ bV,
    const float* __restrict__ vKp, const float* __restrict__ vVp,
    short* __restrict__ Ab, short* __restrict__ Wqkv_t,
    short* __restrict__ WtO, float* __restrict__ bqkv,
    short* __restrict__ Kb2, short* __restrict__ Vt3)
{
    int t = blockIdx.x * 256 + threadIdx.x;
    if (t < NRES) {
        float4 v = *(const float4*)(resid + (size_t)t * 4);
        short4v o = { tobf(v.x), tobf(v.y), tobf(v.z), tobf(v.w) };
        *(short4v*)(Ab + (size_t)t * 4) = o;
        return;
    }
    t -= NRES;
    if (t < NWQ) {
        int cc = t / 768, d = t % 768;
        float w;
        if (cc < 256)      w = WQ[((size_t)(cc >> 4) * DM + d) * 16 + (cc & 15)];
        else if (cc < 512) w = WK[((size_t)((cc - 256) >> 4) * DM + d) * 16 + (cc & 15)];
        else               w = WV[(size_t)(cc - 512) * DM + d];
        Wqkv_t[t] = tobf(w);
        return;
    }
    t -= NWQ;
    if (t < NWO) {
        int c = t & 255, m = t >> 8;
        WtO[t] = tobf(WO[(size_t)c * DM + m]);
        return;
    }
    t -= NWO;
    if (t < 768) {
        bqkv[t] = (t < 256) ? bQ[t] : (t < 512 ? bK[t - 256] : bV[t - 512]);
        return;
    }
    t -= 768;
    if (t < 32 * 32) {               // tails: s in [2048, 2080)
        const int bh = t >> 5;
        const int s  = S_ + (t & 31);
        const int h  = bh & 15;
        short kb[16], vb[16];
        if (s < SK) {
            const int tt = s - S_;
#pragma unroll
            for (int e = 0; e < 16; ++e) {
                kb[e] = tobf(vKp[(size_t)tt * 256 + h * 16 + e]);
                vb[e] = tobf(vVp[(size_t)tt * 256 + h * 16 + e]);
            }
        } else {
#pragma unroll
            for (int e = 0; e < 16; ++e) { kb[e] = 0; vb[e] = 0; }
        }
        const int t5 = s >> 5;       // == 64
        short* kbase = Kb2 + ((size_t)bh * NT_ + t5) * 512 + (s & 31) * 8;
#pragma unroll
        for (int e = 0; e < 8; ++e)  { kbase[e] = kb[e]; kbase[256 + e] = kb[e + 8]; }
        short* vbase = Vt3 + ((size_t)bh * NT_ + t5) * 1024
                     + ((s >> 4) & 1) * 512 + ((s >> 3) & 1) * 8 + (s & 7);
#pragma unroll
        for (int dv = 0; dv < 16; ++dv) vbase[dv * 16] = vb[dv];
    }
}

// ---------------------------------------------------------------------------
// mm_qkv: C = A[4096][768] * Wqkv_t^T + bqkv, FUSED rotary + scatter epilogue.
// ---------------------------------------------------------------------------
__global__ __launch_bounds__(256) void mm_qkv(
    const short* __restrict__ A, const short* __restrict__ Bt,
    const float* __restrict__ bias,
    short* __restrict__ Qb2, short* __restrict__ Kb2, short* __restrict__ Vt3)
{
    __shared__ short As[128 * 64];
    __shared__ short Bs[64 * 64];

    const int tid  = threadIdx.x;
    const int w    = tid >> 6;
    const int lane = tid & 63;
    const int wm   = w >> 1, wn = w & 1;
    const int g    = lane >> 4, c = lane & 15;

    const int linear = blockIdx.y * 12 + blockIdx.x;   // 0..383
    const int xcd  = linear & 7;
    const int jj2  = linear >> 3;                      // 0..47
    const int m0   = (xcd * 4 + jj2 / 12) * 128;
    const int n0   = (jj2 % 12) * 64;

    f32x4 acc[4][2];
#pragma unroll
    for (int i = 0; i < 4; ++i)
#pragma unroll
        for (int j = 0; j < 2; ++j) acc[i][j] = (f32x4){0.f, 0.f, 0.f, 0.f};

    const int lr = lane >> 3;
    const int lc = lane & 7;

    for (int k0 = 0; k0 < 768; k0 += 64) {
#pragma unroll
        for (int i = 0; i < 4; ++i) {
            const int ch  = i * 4 + w;
            const int row = ch * 8 + lr;
            const int scc = lc ^ (row & 7);
            gload_lds16(A + (size_t)(m0 + row) * 768 + k0 + scc * 8, As + ch * 512);
        }
#pragma unroll
        for (int i = 0; i < 2; ++i) {
            const int ch  = i * 4 + w;
            const int row = ch * 8 + lr;
            const int scc = lc ^ (row & 7);
            gload_lds16(Bt + (size_t)(n0 + row) * 768 + k0 + scc * 8, Bs + ch * 512);
        }
        __syncthreads();
#pragma unroll
        for (int kk = 0; kk < 64; kk += 32) {
            short8 af[4], bf[2];
#pragma unroll
            for (int i = 0; i < 4; ++i) {
                const int row = wm * 64 + i * 16 + c;
                const int sc  = ((kk >> 3) + g) ^ (row & 7);
                af[i] = *(const short8*)(As + row * 64 + sc * 8);
            }
#pragma unroll
            for (int j = 0; j < 2; ++j) {
                const int row = wn * 32 + j * 16 + c;
                const int sc  = ((kk >> 3) + g) ^ (row & 7);
                bf[j] = *(const short8*)(Bs + row * 64 + sc * 8);
            }
#pragma unroll
            for (int i = 0; i < 4; ++i)
#pragma unroll
                for (int j = 0; j < 2; ++j)
                    acc[i][j] = __builtin_amdgcn_mfma_f32_16x16x32_bf16(
                        af[i], bf[j], acc[i][j], 0, 0, 0);
        }
        __syncthreads();
    }

    // ---- fused epilogue ----
    const float bv0 = bias[n0 + wn * 32 + c];
    const float bv1 = bias[n0 + wn * 32 + 16 + c];

    if (n0 < 512) {
        const int isQ = (n0 < 256) ? 1 : 0;
        const float invf = __builtin_amdgcn_exp2f(-(float)(c & 7) * L2B8);
        const int h0 = (((n0 + wn * 32) & 255) >> 4);
        const int elo = (c & 8) ? 0 : 1;
#pragma unroll
        for (int i = 0; i < 4; ++i) {
#pragma unroll
            for (int r = 0; r < 4; ++r) {
                const int row = m0 + wm * 64 + i * 16 + 4 * g + r;
                const int s   = row & 2047;
                const int b   = row >> 11;
                float sn, cs;
                __sincosf((float)s * invf, &sn, &cs);
#pragma unroll
                for (int j = 0; j < 2; ++j) {
                    float val = acc[i][j][r] + (j ? bv1 : bv0);
                    float par = __shfl_xor(val, 8);
                    float rot = elo ? -par : par;
                    float out = val * cs + rot * sn;
                    if (isQ) out *= QSCALE;
                    const int bh = b * 16 + h0 + j;
                    const size_t base = isQ
                        ? ((size_t)bh * 64 + (s >> 5)) * 512
                        : ((size_t)bh * NT_ + (s >> 5)) * 512;
                    short* dst = (isQ ? Qb2 : Kb2) + base
                               + (s & 31) * 8 + (c >> 3) * 256 + (c & 7);
                    *dst = tobf(out);
                }
            }
        }
    } else {
        const int h0 = ((n0 + wn * 32 - 512) >> 4);
#pragma unroll
        for (int i = 0; i < 4; ++i) {
#pragma unroll
            for (int r = 0; r < 4; ++r) {
                const int row = m0 + wm * 64 + i * 16 + 4 * g + r;
                const int s   = row & 2047;
                const int b   = row >> 11;
#pragma unroll
                for (int j = 0; j < 2; ++j) {
                    float val = acc[i][j][r] + (j ? bv1 : bv0);
                    const int bh = b * 16 + h0 + j;
                    short* dst = Vt3 + ((size_t)bh * NT_ + (s >> 5)) * 1024
                               + ((s >> 4) & 1) * 512 + ((s >> 3) & 1) * 8 + (s & 7)
                               + c * 16;
                    *dst = tobf(val);
                }
            }
        }
    }
}

// ---------------------------------------------------------------------------
// mm_out: out[4096][768] = Zb[4096][256] * WtO^T + bO  (fp32 out), XCD remap.
// ---------------------------------------------------------------------------
__global__ __launch_bounds__(256) void mm_out(
    const short* __restrict__ A, const short* __restrict__ Bt,
    const float* __restrict__ bias, float* __restrict__ Cout)
{
    __shared__ short As[128 * 64];
    __shared__ short Bs[64 * 64];

    const int tid  = threadIdx.x;
    const int w    = tid >> 6;
    const int lane = tid & 63;
    const int wm   = w >> 1, wn = w & 1;
    const int g    = lane >> 4, c = lane & 15;

    const int linear = blockIdx.y * 12 + blockIdx.x;
    const int xcd  = linear & 7;
    const int jj2  = linear >> 3;
    const int m0   = (xcd * 4 + jj2 / 12) * 128;
    const int n0   = (jj2 % 12) * 64;

    f32x4 acc[4][2];
#pragma unroll
    for (int i = 0; i < 4; ++i)
#pragma unroll
        for (int j = 0; j < 2; ++j) acc[i][j] = (f32x4){0.f, 0.f, 0.f, 0.f};

    const int lr = lane >> 3;
    const int lc = lane & 7;

    for (int k0 = 0; k0 < 256; k0 += 64) {
#pragma unroll
        for (int i = 0; i < 4; ++i) {
            const int ch  = i * 4 + w;
            const int row = ch * 8 + lr;
            const int scc = lc ^ (row & 7);
            gload_lds16(A + (size_t)(m0 + row) * 256 + k0 + scc * 8, As + ch * 512);
        }
#pragma unroll
        for (int i = 0; i < 2; ++i) {
            const int ch  = i * 4 + w;
            const int row = ch * 8 + lr;
            const int scc = lc ^ (row & 7);
            gload_lds16(Bt + (size_t)(n0 + row) * 256 + k0 + scc * 8, Bs + ch * 512);
        }
        __syncthreads();
#pragma unroll
        for (int kk = 0; kk < 64; kk += 32) {
            short8 af[4], bf[2];
#pragma unroll
            for (int i = 0; i < 4; ++i) {
                const int row = wm * 64 + i * 16 + c;
                const int sc  = ((kk >> 3) + g) ^ (row & 7);
                af[i] = *(const short8*)(As + row * 64 + sc * 8);
            }
#pragma unroll
            for (int j = 0; j < 2; ++j) {
                const int row = wn * 32 + j * 16 + c;
                const int sc  = ((kk >> 3) + g) ^ (row & 7);
                bf[j] = *(const short8*)(Bs + row * 64 + sc * 8);
            }
#pragma unroll
            for (int i = 0; i < 4; ++i)
#pragma unroll
                for (int j = 0; j < 2; ++j)
                    acc[i][j] = __builtin_amdgcn_mfma_f32_16x16x32_bf16(
                        af[i], bf[j], acc[i][j], 0, 0, 0);
        }
        __syncthreads();
    }
#pragma unroll
    for (int i = 0; i < 4; ++i)
#pragma unroll
        for (int j = 0; j < 2; ++j) {
            const int col = n0 + wn * 32 + j * 16 + c;
            const float bv = bias[col];
#pragma unroll
            for (int r = 0; r < 4; ++r) {
                const int row = m0 + wm * 64 + i * 16 + 4 * g + r;
                Cout[(size_t)row * DM + col] = acc[i][j][r] + bv;
            }
        }
}

// ---------------------------------------------------------------------------
// attn_split: R13 structure with 2-PAIR-DEEP prefetch (4 tiles / 12 loads in
//  flight). Issue->use distance = 2 pair-iterations (~700 compute cyc),
//  covering HBM-class latency that 1-deep (R8) left exposed.
// ---------------------------------------------------------------------------
__global__ __launch_bounds__(256) void attn_split(
    const short* __restrict__ Qb2, const short* __restrict__ Kb2,
    const short* __restrict__ Vt3, unsigned* __restrict__ PartA,
    float* __restrict__ PartL)
{
    const int w    = threadIdx.x >> 6;
    const int lane = threadIdx.x & 63;
    const int blk  = blockIdx.x;            // 0..1311
    const int xcd  = blk & 7;
    const int j    = blk >> 3;              // 0..163
    const int bhl  = j / 41;                // 0..3
    const int slot = j - bhl * 41;          // 0..40
    const int bh   = xcd * 4 + bhl;
    const int r    = slot * 4 + w;          // 0..163
    int qt, sp;
    if (r < 49)       { sp = 1; qt = 15 + r; }
    else if (r < 82)  { sp = 2; qt = 31 + (r - 49); }
    else if (r < 99)  { sp = 3; qt = 47 + (r - 82); }
    else if (r == 99) { sp = 4; qt = 63; }
    else              { sp = 0; qt = 163 - r; }

    const int nt   = qt + 2;
    const int t0   = sp * TSPLIT;
    const int tend = min(t0 + TSPLIT, nt);

    const int hi = lane >> 5;
    const int qc = lane & 31;
    const int q0 = qt * 32;

    const f32x16 zero16 = {0,0,0,0,0,0,0,0,0,0,0,0,0,0,0,0};

    short8 qf = *(const short8*)(Qb2 + ((size_t)bh * 64 + qt) * 512 + lane * 8);

    f32x16 acc = zero16;
    float lsum = 0.f;

    const short* kbase = Kb2 + (size_t)bh * NT_ * 512 + lane * 8;
    const short* vbase = Vt3 + (size_t)bh * NT_ * 1024 + (lane & 15) * 16 + hi * 8;
    const int qv16  = q0 + qc + 16;
    const int tmask = (q0 + 17) >> 5;      // first tile index needing mask

#define LK(tt)  (*(const short8*)(kbase + (size_t)(tt) * 512))
#define LVA(tt) (*(const short8*)(vbase + (size_t)(tt) * 1024))
#define LVB(tt) (*(const short8*)(vbase + (size_t)(tt) * 1024 + 512))

#define SOFTMAX_TILE(S, tt, B1, B2)                                          \
    {                                                                        \
        if ((tt) >= tmask) {                                                 \
            const int kt_ = (tt) * 32;                                       \
            _Pragma("unroll")                                                \
            for (int rr = 0; rr < 16; ++rr) {                                \
                const int key = kt_ + (rr & 3) + 8 * (rr >> 2) + 4 * hi;     \
                S[rr] = (key <= qv16) ? S[rr] : -INFINITY;                   \
            }                                                                \
        }                                                                    \
        unsigned pk[8];                                                      \
        _Pragma("unroll")                                                    \
        for (int jj = 0; jj < 8; ++jj) {                                     \
            const float p0 = __builtin_amdgcn_exp2f(S[2 * jj]);              \
            const float p1 = __builtin_amdgcn_exp2f(S[2 * jj + 1]);          \
            lsum += p0 + p1;                                                 \
            asm("v_cvt_pk_bf16_f32 %0, %1, %2" : "=v"(pk[jj]) : "v"(p0), "v"(p1)); \
        }                                                                    \
        unsigned a0 = pk[0], a2 = pk[2], a1 = pk[1], a3 = pk[3];             \
        unsigned a4 = pk[4], a6 = pk[6], a5 = pk[5], a7 = pk[7];             \
        asm("v_permlane32_swap_b32 %0, %1" : "+v"(a0), "+v"(a2));            \
        asm("v_permlane32_swap_b32 %0, %1" : "+v"(a1), "+v"(a3));            \
        asm("v_permlane32_swap_b32 %0, %1" : "+v"(a4), "+v"(a6));            \
        asm("v_permlane32_swap_b32 %0, %1" : "+v"(a5), "+v"(a7));            \
        B1.u[0] = a0; B1.u[1] = a1; B1.u[2] = a2; B1.u[3] = a3;              \
        B2.u[0] = a4; B2.u[1] = a5; B2.u[2] = a6; B2.u[3] = a7;              \
    }

    const int npair_end = t0 + ((tend - t0) & ~1);

    if (t0 < npair_end) {
        // pair buffer 0: tiles t, t+1 ; pair buffer 1: tiles t+2, t+3
        short8 kfA0 = LK(t0),     vaA0 = LVA(t0),     vvA0 = LVB(t0);
        short8 kfB0 = LK(t0 + 1), vaB0 = LVA(t0 + 1), vvB0 = LVB(t0 + 1);
        short8 kfA1 = kfA0, vaA1 = vaA0, vvA1 = vvA0;
        short8 kfB1 = kfB0, vaB1 = vaB0, vvB1 = vvB0;
        if (t0 + 2 < npair_end) {
            kfA1 = LK(t0 + 2); vaA1 = LVA(t0 + 2); vvA1 = LVB(t0 + 2);
            kfB1 = LK(t0 + 3); vaB1 = LVA(t0 + 3); vvB1 = LVB(t0 + 3);
        }

        for (int t = t0; t < npair_end; t += 2) {
            // prefetch pair t+4 (2 iterations ahead)
            short8 kfA2 = kfA1, vaA2 = vaA1, vvA2 = vvA1;
            short8 kfB2 = kfB1, vaB2 = vaB1, vvB2 = vvB1;
            if (t + 4 < npair_end) {
                kfA2 = LK(t + 4); vaA2 = LVA(t + 4); vvA2 = LVB(t + 4);
                kfB2 = LK(t + 5); vaB2 = LVA(t + 5); vvB2 = LVB(t + 5);
            }

            __builtin_amdgcn_s_setprio(1);
            f32x16 S0 = __builtin_amdgcn_mfma_f32_32x32x16_bf16(kfA0, qf, zero16, 0, 0, 0);
            f32x16 S1 = __builtin_amdgcn_mfma_f32_32x32x16_bf16(kfB0, qf, zero16, 0, 0, 0);
            __builtin_amdgcn_s_setprio(0);

            union { unsigned u[4]; short8 v; } b1A, b2A, b1B, b2B;
            SOFTMAX_TILE(S0, t,     b1A, b2A);
            SOFTMAX_TILE(S1, t + 1, b1B, b2B);

            __builtin_amdgcn_s_setprio(1);
            acc = __builtin_amdgcn_mfma_f32_32x32x16_bf16(vaA0, b1A.v, acc, 0, 0, 0);
            acc = __builtin_amdgcn_mfma_f32_32x32x16_bf16(vvA0, b2A.v, acc, 0, 0, 0);
            acc = __builtin_amdgcn_mfma_f32_32x32x16_bf16(vaB0, b1B.v, acc, 0, 0, 0);
            acc = __builtin_amdgcn_mfma_f32_32x32x16_bf16(vvB0, b2B.v, acc, 0, 0, 0);
            __builtin_amdgcn_s_setprio(0);

            // rotate buffers
            kfA0 = kfA1; vaA0 = vaA1; vvA0 = vvA1;
            kfB0 = kfB1; vaB0 = vaB1; vvB0 = vvB1;
            kfA1 = kfA2; vaA1 = vaA2; vvA1 = vvA2;
            kfB1 = kfB2; vaB1 = vaB2; vvB1 = vvB2;
        }
    }
    if (npair_end < tend) {                        // odd tail tile
        const int t = npair_end;
        short8 kf = LK(t), va = LVA(t), vv = LVB(t);
        f32x16 S0 = __builtin_amdgcn_mfma_f32_32x32x16_bf16(kf, qf, zero16, 0, 0, 0);
        union { unsigned u[4]; short8 v; } b1, b2;
        SOFTMAX_TILE(S0, t, b1, b2);
        acc = __builtin_amdgcn_mfma_f32_32x32x16_bf16(va, b1.v, acc, 0, 0, 0);
        acc = __builtin_amdgcn_mfma_f32_32x32x16_bf16(vv, b2.v, acc, 0, 0, 0);
    }

    uint4v pa;
    asm("v_cvt_pk_bf16_f32 %0, %1, %2" : "=v"(pa.x) : "v"(acc[0]), "v"(acc[1]));
    asm("v_cvt_pk_bf16_f32 %0, %1, %2" : "=v"(pa.y) : "v"(acc[2]), "v"(acc[3]));
    asm("v_cvt_pk_bf16_f32 %0, %1, %2" : "=v"(pa.z) : "v"(acc[4]), "v"(acc[5]));
    asm("v_cvt_pk_bf16_f32 %0, %1, %2" : "=v"(pa.w) : "v"(acc[6]), "v"(acc[7]));

    const int pidx = (bh * 64 + qt) * MAXSP + sp;
    *(uint4v*)(PartA + ((size_t)pidx * 64 + lane) * 4) = pa;

    lsum += __shfl_xor(lsum, 32);
    if (hi == 0) PartL[(size_t)pidx * 32 + qc] = lsum;
}

// ---------------------------------------------------------------------------
// attn_combine: wave per (bh,qt): sum <=MAXSP partials, normalize, write Z.
// ---------------------------------------------------------------------------
__global__ __launch_bounds__(256) void attn_combine(
    const unsigned* __restrict__ PartA, const float* __restrict__ PartL,
    short* __restrict__ Zb)
{
    const int w    = threadIdx.x >> 6;
    const int lane = threadIdx.x & 63;
    const int wid  = blockIdx.x * 4 + w;
    const int bh   = wid >> 6;
    const int qt   = wid & 63;
    const int hi   = lane >> 5;
    const int qc   = lane & 31;
    const int ns   = (qt + 2 + TSPLIT - 1) / TSPLIT;

    float a[8];
#pragma unroll
    for (int rr = 0; rr < 8; ++rr) a[rr] = 0.f;
    float lsum = 0.f;

    const int pbase = (bh * 64 + qt) * MAXSP;
    for (int sp = 0; sp < ns; ++sp) {
        uint4v pa = *(const uint4v*)(PartA + ((size_t)(pbase + sp) * 64 + lane) * 4);
        a[0] += frombf_lo(pa.x); a[1] += frombf_hi(pa.x);
        a[2] += frombf_lo(pa.y); a[3] += frombf_hi(pa.y);
        a[4] += frombf_lo(pa.z); a[5] += frombf_hi(pa.z);
        a[6] += frombf_lo(pa.w); a[7] += frombf_hi(pa.w);
        lsum += PartL[(size_t)(pbase + sp) * 32 + qc];
    }
    const float inv = 1.f / lsum;

    const int b = bh >> 4, h = bh & 15;
    const int q0 = qt * 32;
    short* zp = Zb + ((size_t)(b * S_ + q0 + qc)) * C_ + h * 16;
    unsigned o01, o23, o45, o67;
    {
        float a0 = a[0] * inv, a1 = a[1] * inv, a2 = a[2] * inv, a3 = a[3] * inv;
        float a4 = a[4] * inv, a5 = a[5] * inv, a6 = a[6] * inv, a7 = a[7] * inv;
        asm("v_cvt_pk_bf16_f32 %0, %1, %2" : "=v"(o01) : "v"(a0), "v"(a1));
        asm("v_cvt_pk_bf16_f32 %0, %1, %2" : "=v"(o23) : "v"(a2), "v"(a3));
        asm("v_cvt_pk_bf16_f32 %0, %1, %2" : "=v"(o45) : "v"(a4), "v"(a5));
        asm("v_cvt_pk_bf16_f32 %0, %1, %2" : "=v"(o67) : "v"(a6), "v"(a7));
    }
    *(unsigned*)(zp + 4 * hi)         = o01;
    *(unsigned*)(zp + 4 * hi + 2)     = o23;
    *(unsigned*)(zp + 8 + 4 * hi)     = o45;
    *(unsigned*)(zp + 8 + 4 * hi + 2) = o67;
}

extern "C" void kernel_launch(void* const* d_in, const int* in_sizes, int n_in,
                              void* d_out, int out_size, void* d_ws, size_t ws_size,
                              hipStream_t stream)
{
    const float* resid = (const float*)d_in[0];
    const float* WQ = (const float*)d_in[1];
    const float* WK = (const float*)d_in[2];
    const float* WV = (const float*)d_in[3];
    const float* WO = (const float*)d_in[4];
    const float* bQ = (const float*)d_in[5];
    const float* bK = (const float*)d_in[6];
    const float* bV = (const float*)d_in[7];
    const float* bO = (const float*)d_in[8];
    const float* vK = (const float*)d_in[9];
    const float* vV = (const float*)d_in[10];
    float* out = (float*)d_out;
    float* ws  = (float*)d_ws;

    short* Zb   = (short*)ws;                       // 4096*256 bf16
    float* bqkv = ws + 3145728;                     // 768 f32
    short* Ab   = (short*)(ws + 3145728 + 768);     // 3,145,728 bf16
    short* Wqt  = Ab + 3145728;                     // 589,824
    short* WtO  = Wqt + 589824;                     // 196,608
    short* Qb2  = WtO + 196608;                     // 32*64*512  = 1,048,576
    short* Kb2  = Qb2 + 1048576;                    // 32*65*512  = 1,064,960
    short* Vt3  = Kb2 + 1064960;                    // 32*65*1024 = 2,129,920
    unsigned* PartA = (unsigned*)(Vt3 + 2129920);   // 10240*64*4 u32
    float*    PartL = (float*)(PartA + 2621440);    // 10240*32 f32

    const int conv_total = NRES + NWQ + NWO + 768 + 1024;
    conv_all<<<dim3((conv_total + 255) / 256), 256, 0, stream>>>(
        resid, WQ, WK, WV, WO, bQ, bK, bV, vK, vV,
        Ab, Wqt, WtO, bqkv, Kb2, Vt3);
    mm_qkv<<<dim3(12, 32), 256, 0, stream>>>(Ab, Wqt, bqkv, Qb2, Kb2, Vt3);
    attn_split<<<dim3(32 * NACT / 4), 256, 0, stream>>>(Qb2, Kb2, Vt3, PartA, PartL);
    attn_combine<<<dim3(512), 256, 0, stream>>>(PartA, PartL, Zb);
    mm_out<<<dim3(12, 32), 256, 0, stream>>>(Zb, WtO, bO, out);
}

// Round 15
// 61.440 us; speedup vs baseline: 1.0262x; 1.0262x over previous
//
#include <hip/hip_runtime.h>
#include <hip/hip_bf16.h>
#include <math.h>

// Problem constants
#define B_   2
#define S_   2048
#define DM   768
#define H_   16      // N_QK
#define C_   256     // N_OV
#define VKV_ 16
#define SK   2064    // S_ + VKV_
#define SKP  2080
#define NT_  65      // key tiles per bh

#define TSPLIT 16
#define MAXSP  5     // ceil(65/16)
#define NACT   164   // active (qt,sp) pairs per bh

typedef __attribute__((ext_vector_type(8))) short short8;    // 8 bf16
typedef __attribute__((ext_vector_type(4))) short short4v;
typedef __attribute__((ext_vector_type(4))) float f32x4;
typedef __attribute__((ext_vector_type(16))) float f32x16;
typedef __attribute__((ext_vector_type(4))) unsigned uint4v;

// log2(e) / SCALE folded into Q so p = exp2(s)
#define QSCALE 0.360673760222240851f
// log2(10000)/8
#define L2B8   1.6609640474436811f

__device__ __forceinline__ short tobf(float f) {
    union { float f; unsigned u; } x; x.f = f;
    unsigned r = x.u + 0x7FFFu + ((x.u >> 16) & 1u);   // RNE
    return (short)(r >> 16);
}
__device__ __forceinline__ float frombf_lo(unsigned u) {
    union { unsigned u; float f; } x; x.u = u << 16; return x.f;
}
__device__ __forceinline__ float frombf_hi(unsigned u) {
    union { unsigned u; float f; } x; x.u = u & 0xFFFF0000u; return x.f;
}

__device__ __forceinline__ void gload_lds16(const short* g, short* l) {
    __builtin_amdgcn_global_load_lds(
        (const __attribute__((address_space(1))) unsigned int*)g,
        (__attribute__((address_space(3))) unsigned int*)l, 16, 0, 0);
}

// ---------------------------------------------------------------------------
// conv_all: resid->bf16, weights pack, bias pack, K/V tail (s>=2048) init.
// ---------------------------------------------------------------------------
#define NRES (4096*768/4)
#define NWQ  (768*768)
#define NWO  (768*256)
__global__ __launch_bounds__(256) void conv_all(
    const float* __restrict__ resid,
    const float* __restrict__ WQ, const float* __restrict__ WK,
    const float* __restrict__ WV, const float* __restrict__ WO,
    const float* __restrict__ bQ, const float* __restrict__ bK,
    const float* __restrict__ bV,
    const float* __restrict__ vKp, const float* __restrict__ vVp,
    short* __restrict__ Ab, short* __restrict__ Wqkv_t,
    short* __restrict__ WtO, float* __restrict__ bqkv,
    short* __restrict__ Kb2, short* __restrict__ Vt3)
{
    int t = blockIdx.x * 256 + threadIdx.x;
    if (t < NRES) {
        float4 v = *(const float4*)(resid + (size_t)t * 4);
        short4v o = { tobf(v.x), tobf(v.y), tobf(v.z), tobf(v.w) };
        *(short4v*)(Ab + (size_t)t * 4) = o;
        return;
    }
    t -= NRES;
    if (t < NWQ) {
        int cc = t / 768, d = t % 768;
        float w;
        if (cc < 256)      w = WQ[((size_t)(cc >> 4) * DM + d) * 16 + (cc & 15)];
        else if (cc < 512) w = WK[((size_t)((cc - 256) >> 4) * DM + d) * 16 + (cc & 15)];
        else               w = WV[(size_t)(cc - 512) * DM + d];
        Wqkv_t[t] = tobf(w);
        return;
    }
    t -= NWQ;
    if (t < NWO) {
        int c = t & 255, m = t >> 8;
        WtO[t] = tobf(WO[(size_t)c * DM + m]);
        return;
    }
    t -= NWO;
    if (t < 768) {
        bqkv[t] = (t < 256) ? bQ[t] : (t < 512 ? bK[t - 256] : bV[t - 512]);
        return;
    }
    t -= 768;
    if (t < 32 * 32) {               // tails: s in [2048, 2080)
        const int bh = t >> 5;
        const int s  = S_ + (t & 31);
        const int h  = bh & 15;
        short kb[16], vb[16];
        if (s < SK) {
            const int tt = s - S_;
#pragma unroll
            for (int e = 0; e < 16; ++e) {
                kb[e] = tobf(vKp[(size_t)tt * 256 + h * 16 + e]);
                vb[e] = tobf(vVp[(size_t)tt * 256 + h * 16 + e]);
            }
        } else {
#pragma unroll
            for (int e = 0; e < 16; ++e) { kb[e] = 0; vb[e] = 0; }
        }
        const int t5 = s >> 5;       // == 64
        short* kbase = Kb2 + ((size_t)bh * NT_ + t5) * 512 + (s & 31) * 8;
#pragma unroll
        for (int e = 0; e < 8; ++e)  { kbase[e] = kb[e]; kbase[256 + e] = kb[e + 8]; }
        short* vbase = Vt3 + ((size_t)bh * NT_ + t5) * 1024
                     + ((s >> 4) & 1) * 512 + ((s >> 3) & 1) * 8 + (s & 7);
#pragma unroll
        for (int dv = 0; dv < 16; ++dv) vbase[dv * 16] = vb[dv];
    }
}

// ---------------------------------------------------------------------------
// mm_qkv: C = A[4096][768] * Wqkv_t^T + bqkv, FUSED rotary + scatter epilogue.
//  2-PHASE pipeline: stage(t+1) issued BEFORE compute(t); single syncthreads
//  per K-step -> the vmcnt(0) drain lands after 32 MFMAs of cover (T3-min,
//  m248 recipe). Double-buffered LDS (48 KB).
// ---------------------------------------------------------------------------
__global__ __launch_bounds__(256) void mm_qkv(
    const short* __restrict__ A, const short* __restrict__ Bt,
    const float* __restrict__ bias,
    short* __restrict__ Qb2, short* __restrict__ Kb2, short* __restrict__ Vt3)
{
    __shared__ short As[2][128 * 64];
    __shared__ short Bs[2][64 * 64];

    const int tid  = threadIdx.x;
    const int w    = tid >> 6;
    const int lane = tid & 63;
    const int wm   = w >> 1, wn = w & 1;
    const int g    = lane >> 4, c = lane & 15;

    const int linear = blockIdx.y * 12 + blockIdx.x;   // 0..383
    const int xcd  = linear & 7;
    const int jj2  = linear >> 3;                      // 0..47
    const int m0   = (xcd * 4 + jj2 / 12) * 128;
    const int n0   = (jj2 % 12) * 64;

    f32x4 acc[4][2];
#pragma unroll
    for (int i = 0; i < 4; ++i)
#pragma unroll
        for (int j = 0; j < 2; ++j) acc[i][j] = (f32x4){0.f, 0.f, 0.f, 0.f};

    const int lr = lane >> 3;
    const int lc = lane & 7;

#define MMSTAGE(k0v, buf) do {                                               \
        _Pragma("unroll")                                                    \
        for (int i = 0; i < 4; ++i) {                                        \
            const int ch  = i * 4 + w;                                       \
            const int row = ch * 8 + lr;                                     \
            const int scc = lc ^ (row & 7);                                  \
            gload_lds16(A + (size_t)(m0 + row) * 768 + (k0v) + scc * 8,      \
                        &As[buf][ch * 512]);                                 \
        }                                                                    \
        _Pragma("unroll")                                                    \
        for (int i = 0; i < 2; ++i) {                                        \
            const int ch  = i * 4 + w;                                       \
            const int row = ch * 8 + lr;                                     \
            const int scc = lc ^ (row & 7);                                  \
            gload_lds16(Bt + (size_t)(n0 + row) * 768 + (k0v) + scc * 8,     \
                        &Bs[buf][ch * 512]);                                 \
        }                                                                    \
    } while (0)

    MMSTAGE(0, 0);
    __syncthreads();

    for (int kt = 0; kt < 12; ++kt) {
        if (kt + 1 < 12) MMSTAGE((kt + 1) * 64, (kt + 1) & 1);
        const short* Ab_ = &As[kt & 1][0];
        const short* Bb_ = &Bs[kt & 1][0];
#pragma unroll
        for (int kk = 0; kk < 64; kk += 32) {
            short8 af[4], bf[2];
#pragma unroll
            for (int i = 0; i < 4; ++i) {
                const int row = wm * 64 + i * 16 + c;
                const int sc  = ((kk >> 3) + g) ^ (row & 7);
                af[i] = *(const short8*)(Ab_ + row * 64 + sc * 8);
            }
#pragma unroll
            for (int j = 0; j < 2; ++j) {
                const int row = wn * 32 + j * 16 + c;
                const int sc  = ((kk >> 3) + g) ^ (row & 7);
                bf[j] = *(const short8*)(Bb_ + row * 64 + sc * 8);
            }
#pragma unroll
            for (int i = 0; i < 4; ++i)
#pragma unroll
                for (int j = 0; j < 2; ++j)
                    acc[i][j] = __builtin_amdgcn_mfma_f32_16x16x32_bf16(
                        af[i], bf[j], acc[i][j], 0, 0, 0);
        }
        __syncthreads();
    }
#undef MMSTAGE

    // ---- fused epilogue ----
    const float bv0 = bias[n0 + wn * 32 + c];
    const float bv1 = bias[n0 + wn * 32 + 16 + c];

    if (n0 < 512) {
        const int isQ = (n0 < 256) ? 1 : 0;
        const float invf = __builtin_amdgcn_exp2f(-(float)(c & 7) * L2B8);
        const int h0 = (((n0 + wn * 32) & 255) >> 4);
        const int elo = (c & 8) ? 0 : 1;
#pragma unroll
        for (int i = 0; i < 4; ++i) {
#pragma unroll
            for (int r = 0; r < 4; ++r) {
                const int row = m0 + wm * 64 + i * 16 + 4 * g + r;
                const int s   = row & 2047;
                const int b   = row >> 11;
                float sn, cs;
                __sincosf((float)s * invf, &sn, &cs);
#pragma unroll
                for (int j = 0; j < 2; ++j) {
                    float val = acc[i][j][r] + (j ? bv1 : bv0);
                    float par = __shfl_xor(val, 8);
                    float rot = elo ? -par : par;
                    float out = val * cs + rot * sn;
                    if (isQ) out *= QSCALE;
                    const int bh = b * 16 + h0 + j;
                    const size_t base = isQ
                        ? ((size_t)bh * 64 + (s >> 5)) * 512
                        : ((size_t)bh * NT_ + (s >> 5)) * 512;
                    short* dst = (isQ ? Qb2 : Kb2) + base
                               + (s & 31) * 8 + (c >> 3) * 256 + (c & 7);
                    *dst = tobf(out);
                }
            }
        }
    } else {
        const int h0 = ((n0 + wn * 32 - 512) >> 4);
#pragma unroll
        for (int i = 0; i < 4; ++i) {
#pragma unroll
            for (int r = 0; r < 4; ++r) {
                const int row = m0 + wm * 64 + i * 16 + 4 * g + r;
                const int s   = row & 2047;
                const int b   = row >> 11;
#pragma unroll
                for (int j = 0; j < 2; ++j) {
                    float val = acc[i][j][r] + (j ? bv1 : bv0);
                    const int bh = b * 16 + h0 + j;
                    short* dst = Vt3 + ((size_t)bh * NT_ + (s >> 5)) * 1024
                               + ((s >> 4) & 1) * 512 + ((s >> 3) & 1) * 8 + (s & 7)
                               + c * 16;
                    *dst = tobf(val);
                }
            }
        }
    }
}

// ---------------------------------------------------------------------------
// mm_out: out[4096][768] = Zb[4096][256] * WtO^T + bO, 2-phase pipeline.
// ---------------------------------------------------------------------------
__global__ __launch_bounds__(256) void mm_out(
    const short* __restrict__ A, const short* __restrict__ Bt,
    const float* __restrict__ bias, float* __restrict__ Cout)
{
    __shared__ short As[2][128 * 64];
    __shared__ short Bs[2][64 * 64];

    const int tid  = threadIdx.x;
    const int w    = tid >> 6;
    const int lane = tid & 63;
    const int wm   = w >> 1, wn = w & 1;
    const int g    = lane >> 4, c = lane & 15;

    const int linear = blockIdx.y * 12 + blockIdx.x;
    const int xcd  = linear & 7;
    const int jj2  = linear >> 3;
    const int m0   = (xcd * 4 + jj2 / 12) * 128;
    const int n0   = (jj2 % 12) * 64;

    f32x4 acc[4][2];
#pragma unroll
    for (int i = 0; i < 4; ++i)
#pragma unroll
        for (int j = 0; j < 2; ++j) acc[i][j] = (f32x4){0.f, 0.f, 0.f, 0.f};

    const int lr = lane >> 3;
    const int lc = lane & 7;

#define MMSTAGE2(k0v, buf) do {                                              \
        _Pragma("unroll")                                                    \
        for (int i = 0; i < 4; ++i) {                                        \
            const int ch  = i * 4 + w;                                       \
            const int row = ch * 8 + lr;                                     \
            const int scc = lc ^ (row & 7);                                  \
            gload_lds16(A + (size_t)(m0 + row) * 256 + (k0v) + scc * 8,      \
                        &As[buf][ch * 512]);                                 \
        }                                                                    \
        _Pragma("unroll")                                                    \
        for (int i = 0; i < 2; ++i) {                                        \
            const int ch  = i * 4 + w;                                       \
            const int row = ch * 8 + lr;                                     \
            const int scc = lc ^ (row & 7);                                  \
            gload_lds16(Bt + (size_t)(n0 + row) * 256 + (k0v) + scc * 8,     \
                        &Bs[buf][ch * 512]);                                 \
        }                                                                    \
    } while (0)

    MMSTAGE2(0, 0);
    __syncthreads();

    for (int kt = 0; kt < 4; ++kt) {
        if (kt + 1 < 4) MMSTAGE2((kt + 1) * 64, (kt + 1) & 1);
        const short* Ab_ = &As[kt & 1][0];
        const short* Bb_ = &Bs[kt & 1][0];
#pragma unroll
        for (int kk = 0; kk < 64; kk += 32) {
            short8 af[4], bf[2];
#pragma unroll
            for (int i = 0; i < 4; ++i) {
                const int row = wm * 64 + i * 16 + c;
                const int sc  = ((kk >> 3) + g) ^ (row & 7);
                af[i] = *(const short8*)(Ab_ + row * 64 + sc * 8);
            }
#pragma unroll
            for (int j = 0; j < 2; ++j) {
                const int row = wn * 32 + j * 16 + c;
                const int sc  = ((kk >> 3) + g) ^ (row & 7);
                bf[j] = *(const short8*)(Bb_ + row * 64 + sc * 8);
            }
#pragma unroll
            for (int i = 0; i < 4; ++i)
#pragma unroll
                for (int j = 0; j < 2; ++j)
                    acc[i][j] = __builtin_amdgcn_mfma_f32_16x16x32_bf16(
                        af[i], bf[j], acc[i][j], 0, 0, 0);
        }
        __syncthreads();
    }
#undef MMSTAGE2

#pragma unroll
    for (int i = 0; i < 4; ++i)
#pragma unroll
        for (int j = 0; j < 2; ++j) {
            const int col = n0 + wn * 32 + j * 16 + c;
            const float bv = bias[col];
#pragma unroll
            for (int r = 0; r < 4; ++r) {
                const int row = m0 + wm * 64 + i * 16 + 4 * g + r;
                Cout[(size_t)row * DM + col] = acc[i][j][r] + bv;
            }
        }
}

// ---------------------------------------------------------------------------
// attn_split: R13-exact (paired key-tile loop, 1-deep prefetch, XCD-affine
//  bh mapping, setprio around MFMA clusters). Proven 60.1 us config.
// ---------------------------------------------------------------------------
__global__ __launch_bounds__(256) void attn_split(
    const short* __restrict__ Qb2, const short* __restrict__ Kb2,
    const short* __restrict__ Vt3, unsigned* __restrict__ PartA,
    float* __restrict__ PartL)
{
    const int w    = threadIdx.x >> 6;
    const int lane = threadIdx.x & 63;
    const int blk  = blockIdx.x;            // 0..1311
    const int xcd  = blk & 7;
    const int j    = blk >> 3;              // 0..163
    const int bhl  = j / 41;                // 0..3
    const int slot = j - bhl * 41;          // 0..40
    const int bh   = xcd * 4 + bhl;
    const int r    = slot * 4 + w;          // 0..163
    int qt, sp;
    if (r < 49)       { sp = 1; qt = 15 + r; }
    else if (r < 82)  { sp = 2; qt = 31 + (r - 49); }
    else if (r < 99)  { sp = 3; qt = 47 + (r - 82); }
    else if (r == 99) { sp = 4; qt = 63; }
    else              { sp = 0; qt = 163 - r; }

    const int nt   = qt + 2;
    const int t0   = sp * TSPLIT;
    const int tend = min(t0 + TSPLIT, nt);

    const int hi = lane >> 5;
    const int qc = lane & 31;
    const int q0 = qt * 32;

    const f32x16 zero16 = {0,0,0,0,0,0,0,0,0,0,0,0,0,0,0,0};

    short8 qf = *(const short8*)(Qb2 + ((size_t)bh * 64 + qt) * 512 + lane * 8);

    f32x16 acc = zero16;
    float lsum = 0.f;

    const short* kbase = Kb2 + (size_t)bh * NT_ * 512 + lane * 8;
    const short* vbase = Vt3 + (size_t)bh * NT_ * 1024 + (lane & 15) * 16 + hi * 8;
    const int qv16  = q0 + qc + 16;
    const int tmask = (q0 + 17) >> 5;      // first tile index needing mask

#define LK(tt)  (*(const short8*)(kbase + (size_t)(tt) * 512))
#define LVA(tt) (*(const short8*)(vbase + (size_t)(tt) * 1024))
#define LVB(tt) (*(const short8*)(vbase + (size_t)(tt) * 1024 + 512))

#define SOFTMAX_TILE(S, tt, B1, B2)                                          \
    {                                                                        \
        if ((tt) >= tmask) {                                                 \
            const int kt_ = (tt) * 32;                                       \
            _Pragma("unroll")                                                \
            for (int rr = 0; rr < 16; ++rr) {                                \
                const int key = kt_ + (rr & 3) + 8 * (rr >> 2) + 4 * hi;     \
                S[rr] = (key <= qv16) ? S[rr] : -INFINITY;                   \
            }                                                                \
        }                                                                    \
        unsigned pk[8];                                                      \
        _Pragma("unroll")                                                    \
        for (int jj = 0; jj < 8; ++jj) {                                     \
            const float p0 = __builtin_amdgcn_exp2f(S[2 * jj]);              \
            const float p1 = __builtin_amdgcn_exp2f(S[2 * jj + 1]);          \
            lsum += p0 + p1;                                                 \
            asm("v_cvt_pk_bf16_f32 %0, %1, %2" : "=v"(pk[jj]) : "v"(p0), "v"(p1)); \
        }                                                                    \
        unsigned a0 = pk[0], a2 = pk[2], a1 = pk[1], a3 = pk[3];             \
        unsigned a4 = pk[4], a6 = pk[6], a5 = pk[5], a7 = pk[7];             \
        asm("v_permlane32_swap_b32 %0, %1" : "+v"(a0), "+v"(a2));            \
        asm("v_permlane32_swap_b32 %0, %1" : "+v"(a1), "+v"(a3));            \
        asm("v_permlane32_swap_b32 %0, %1" : "+v"(a4), "+v"(a6));            \
        asm("v_permlane32_swap_b32 %0, %1" : "+v"(a5), "+v"(a7));            \
        B1.u[0] = a0; B1.u[1] = a1; B1.u[2] = a2; B1.u[3] = a3;              \
        B2.u[0] = a4; B2.u[1] = a5; B2.u[2] = a6; B2.u[3] = a7;              \
    }

    const int npair_end = t0 + ((tend - t0) & ~1);

    if (t0 < npair_end) {
        short8 kfA = LK(t0),     vaA = LVA(t0),     vvA = LVB(t0);
        short8 kfB = LK(t0 + 1), vaB = LVA(t0 + 1), vvB = LVB(t0 + 1);

        for (int t = t0; t < npair_end; t += 2) {
            short8 kfA_n = kfA, vaA_n = vaA, vvA_n = vvA;
            short8 kfB_n = kfB, vaB_n = vaB, vvB_n = vvB;
            if (t + 2 < npair_end) {
                kfA_n = LK(t + 2); vaA_n = LVA(t + 2); vvA_n = LVB(t + 2);
                kfB_n = LK(t + 3); vaB_n = LVA(t + 3); vvB_n = LVB(t + 3);
            }

            __builtin_amdgcn_s_setprio(1);
            f32x16 S0 = __builtin_amdgcn_mfma_f32_32x32x16_bf16(kfA, qf, zero16, 0, 0, 0);
            f32x16 S1 = __builtin_amdgcn_mfma_f32_32x32x16_bf16(kfB, qf, zero16, 0, 0, 0);
            __builtin_amdgcn_s_setprio(0);

            union { unsigned u[4]; short8 v; } b1A, b2A, b1B, b2B;
            SOFTMAX_TILE(S0, t,     b1A, b2A);
            SOFTMAX_TILE(S1, t + 1, b1B, b2B);

            __builtin_amdgcn_s_setprio(1);
            acc = __builtin_amdgcn_mfma_f32_32x32x16_bf16(vaA, b1A.v, acc, 0, 0, 0);
            acc = __builtin_amdgcn_mfma_f32_32x32x16_bf16(vvA, b2A.v, acc, 0, 0, 0);
            acc = __builtin_amdgcn_mfma_f32_32x32x16_bf16(vaB, b1B.v, acc, 0, 0, 0);
            acc = __builtin_amdgcn_mfma_f32_32x32x16_bf16(vvB, b2B.v, acc, 0, 0, 0);
            __builtin_amdgcn_s_setprio(0);

            kfA = kfA_n; vaA = vaA_n; vvA = vvA_n;
            kfB = kfB_n; vaB = vaB_n; vvB = vvB_n;
        }
    }
    if (npair_end < tend) {                        // odd tail tile
        const int t = npair_end;
        short8 kf = LK(t), va = LVA(t), vv = LVB(t);
        f32x16 S0 = __builtin_amdgcn_mfma_f32_32x32x16_bf16(kf, qf, zero16, 0, 0, 0);
        union { unsigned u[4]; short8 v; } b1, b2;
        SOFTMAX_TILE(S0, t, b1, b2);
        acc = __builtin_amdgcn_mfma_f32_32x32x16_bf16(va, b1.v, acc, 0, 0, 0);
        acc = __builtin_amdgcn_mfma_f32_32x32x16_bf16(vv, b2.v, acc, 0, 0, 0);
    }

    uint4v pa;
    asm("v_cvt_pk_bf16_f32 %0, %1, %2" : "=v"(pa.x) : "v"(acc[0]), "v"(acc[1]));
    asm("v_cvt_pk_bf16_f32 %0, %1, %2" : "=v"(pa.y) : "v"(acc[2]), "v"(acc[3]));
    asm("v_cvt_pk_bf16_f32 %0, %1, %2" : "=v"(pa.z) : "v"(acc[4]), "v"(acc[5]));
    asm("v_cvt_pk_bf16_f32 %0, %1, %2" : "=v"(pa.w) : "v"(acc[6]), "v"(acc[7]));

    const int pidx = (bh * 64 + qt) * MAXSP + sp;
    *(uint4v*)(PartA + ((size_t)pidx * 64 + lane) * 4) = pa;

    lsum += __shfl_xor(lsum, 32);
    if (hi == 0) PartL[(size_t)pidx * 32 + qc] = lsum;
}

// ---------------------------------------------------------------------------
// attn_combine: wave per (bh,qt): sum <=MAXSP partials, normalize, write Z.
// ---------------------------------------------------------------------------
__global__ __launch_bounds__(256) void attn_combine(
    const unsigned* __restrict__ PartA, const float* __restrict__ PartL,
    short* __restrict__ Zb)
{
    const int w    = threadIdx.x >> 6;
    const int lane = threadIdx.x & 63;
    const int wid  = blockIdx.x * 4 + w;
    const int bh   = wid >> 6;
    const int qt   = wid & 63;
    const int hi   = lane >> 5;
    const int qc   = lane & 31;
    const int ns   = (qt + 2 + TSPLIT - 1) / TSPLIT;

    float a[8];
#pragma unroll
    for (int rr = 0; rr < 8; ++rr) a[rr] = 0.f;
    float lsum = 0.f;

    const int pbase = (bh * 64 + qt) * MAXSP;
    for (int sp = 0; sp < ns; ++sp) {
        uint4v pa = *(const uint4v*)(PartA + ((size_t)(pbase + sp) * 64 + lane) * 4);
        a[0] += frombf_lo(pa.x); a[1] += frombf_hi(pa.x);
        a[2] += frombf_lo(pa.y); a[3] += frombf_hi(pa.y);
        a[4] += frombf_lo(pa.z); a[5] += frombf_hi(pa.z);
        a[6] += frombf_lo(pa.w); a[7] += frombf_hi(pa.w);
        lsum += PartL[(size_t)(pbase + sp) * 32 + qc];
    }
    const float inv = 1.f / lsum;

    const int b = bh >> 4, h = bh & 15;
    const int q0 = qt * 32;
    short* zp = Zb + ((size_t)(b * S_ + q0 + qc)) * C_ + h * 16;
    unsigned o01, o23, o45, o67;
    {
        float a0 = a[0] * inv, a1 = a[1] * inv, a2 = a[2] * inv, a3 = a[3] * inv;
        float a4 = a[4] * inv, a5 = a[5] * inv, a6 = a[6] * inv, a7 = a[7] * inv;
        asm("v_cvt_pk_bf16_f32 %0, %1, %2" : "=v"(o01) : "v"(a0), "v"(a1));
        asm("v_cvt_pk_bf16_f32 %0, %1, %2" : "=v"(o23) : "v"(a2), "v"(a3));
        asm("v_cvt_pk_bf16_f32 %0, %1, %2" : "=v"(o45) : "v"(a4), "v"(a5));
        asm("v_cvt_pk_bf16_f32 %0, %1, %2" : "=v"(o67) : "v"(a6), "v"(a7));
    }
    *(unsigned*)(zp + 4 * hi)         = o01;
    *(unsigned*)(zp + 4 * hi + 2)     = o23;
    *(unsigned*)(zp + 8 + 4 * hi)     = o45;
    *(unsigned*)(zp + 8 + 4 * hi + 2) = o67;
}

extern "C" void kernel_launch(void* const* d_in, const int* in_sizes, int n_in,
                              void* d_out, int out_size, void* d_ws, size_t ws_size,
                              hipStream_t stream)
{
    const float* resid = (const float*)d_in[0];
    const float* WQ = (const float*)d_in[1];
    const float* WK = (const float*)d_in[2];
    const float* WV = (const float*)d_in[3];
    const float* WO = (const float*)d_in[4];
    const float* bQ = (const float*)d_in[5];
    const float* bK = (const float*)d_in[6];
    const float* bV = (const float*)d_in[7];
    const float* bO = (const float*)d_in[8];
    const float* vK = (const float*)d_in[9];
    const float* vV = (const float*)d_in[10];
    float* out = (float*)d_out;
    float* ws  = (float*)d_ws;

    short* Zb   = (short*)ws;                       // 4096*256 bf16
    float* bqkv = ws + 3145728;                     // 768 f32
    short* Ab   = (short*)(ws + 3145728 + 768);     // 3,145,728 bf16
    short* Wqt  = Ab + 3145728;                     // 589,824
    short* WtO  = Wqt + 589824;                     // 196,608
    short* Qb2  = WtO + 196608;                     // 32*64*512  = 1,048,576
    short* Kb2  = Qb2 + 1048576;                    // 32*65*512  = 1,064,960
    short* Vt3  = Kb2 + 1064960;                    // 32*65*1024 = 2,129,920
    unsigned* PartA = (unsigned*)(Vt3 + 2129920);   // 10240*64*4 u32
    float*    PartL = (float*)(PartA + 2621440);    // 10240*32 f32

    const int conv_total = NRES + NWQ + NWO + 768 + 1024;
    conv_all<<<dim3((conv_total + 255) / 256), 256, 0, stream>>>(
        resid, WQ, WK, WV, WO, bQ, bK, bV, vK, vV,
        Ab, Wqt, WtO, bqkv, Kb2, Vt3);
    mm_qkv<<<dim3(12, 32), 256, 0, stream>>>(Ab, Wqt, bqkv, Qb2, Kb2, Vt3);
    attn_split<<<dim3(32 * NACT / 4), 256, 0, stream>>>(Qb2, Kb2, Vt3, PartA, PartL);
    attn_combine<<<dim3(512), 256, 0, stream>>>(PartA, PartL, Zb);
    mm_out<<<dim3(12, 32), 256, 0, stream>>>(Zb, WtO, bO, out);
}

// Round 16
// 58.209 us; speedup vs baseline: 1.0832x; 1.0555x over previous
//
#include <hip/hip_runtime.h>
#include <hip/hip_bf16.h>
#include <math.h>

// Problem constants
#define B_   2
#define S_   2048
#define DM   768
#define H_   16      // N_QK
#define C_   256     // N_OV
#define VKV_ 16
#define SK   2064    // S_ + VKV_
#define SKP  2080
#define NT_  65      // key tiles per bh

#define TSPLIT 16
#define MAXSP  5     // ceil(65/16)
#define NACT   164   // active (qt,sp) pairs per bh

typedef __attribute__((ext_vector_type(8))) short short8;    // 8 bf16
typedef __attribute__((ext_vector_type(4))) short short4v;
typedef __attribute__((ext_vector_type(4))) float f32x4;
typedef __attribute__((ext_vector_type(16))) float f32x16;
typedef __attribute__((ext_vector_type(4))) unsigned uint4v;

// log2(e) / SCALE folded into Q so p = exp2(s)
#define QSCALE 0.360673760222240851f
// log2(10000)/8
#define L2B8   1.6609640474436811f

__device__ __forceinline__ short tobf(float f) {
    union { float f; unsigned u; } x; x.f = f;
    unsigned r = x.u + 0x7FFFu + ((x.u >> 16) & 1u);   // RNE
    return (short)(r >> 16);
}
__device__ __forceinline__ float frombf_lo(unsigned u) {
    union { unsigned u; float f; } x; x.u = u << 16; return x.f;
}
__device__ __forceinline__ float frombf_hi(unsigned u) {
    union { unsigned u; float f; } x; x.u = u & 0xFFFF0000u; return x.f;
}

__device__ __forceinline__ void gload_lds16(const short* g, short* l) {
    __builtin_amdgcn_global_load_lds(
        (const __attribute__((address_space(1))) unsigned int*)g,
        (__attribute__((address_space(3))) unsigned int*)l, 16, 0, 0);
}

// ---------------------------------------------------------------------------
// conv_all: resid->bf16, weights pack (Q/K gather COALESCED via bijective
// remap: 16 consecutive threads read 16 contiguous floats), bias, K/V tails.
// ---------------------------------------------------------------------------
#define NRES (4096*768/4)
#define NWQ  (768*768)
#define NWO  (768*256)
__global__ __launch_bounds__(256) void conv_all(
    const float* __restrict__ resid,
    const float* __restrict__ WQ, const float* __restrict__ WK,
    const float* __restrict__ WV, const float* __restrict__ WO,
    const float* __restrict__ bQ, const float* __restrict__ bK,
    const float* __restrict__ bV,
    const float* __restrict__ vKp, const float* __restrict__ vVp,
    short* __restrict__ Ab, short* __restrict__ Wqkv_t,
    short* __restrict__ WtO, float* __restrict__ bqkv,
    short* __restrict__ Kb2, short* __restrict__ Vt3)
{
    int t = blockIdx.x * 256 + threadIdx.x;
    if (t < NRES) {
        float4 v = *(const float4*)(resid + (size_t)t * 4);
        short4v o = { tobf(v.x), tobf(v.y), tobf(v.z), tobf(v.w) };
        *(short4v*)(Ab + (size_t)t * 4) = o;
        return;
    }
    t -= NRES;
    if (t < NWQ) {
        int cc, d;
        if (t < 512 * 768) {            // Q,K: remap so reads are contiguous
            const int e    = t & 15;
            const int rest = t >> 4;
            d  = rest % 768;
            cc = (rest / 768) * 16 + e; // 0..511
        } else { cc = t / 768; d = t % 768; }
        float w;
        if (cc < 256)      w = WQ[((size_t)(cc >> 4) * DM + d) * 16 + (cc & 15)];
        else if (cc < 512) w = WK[((size_t)((cc - 256) >> 4) * DM + d) * 16 + (cc & 15)];
        else               w = WV[(size_t)(cc - 512) * DM + d];
        Wqkv_t[(size_t)cc * 768 + d] = tobf(w);
        return;
    }
    t -= NWQ;
    if (t < NWO) {
        int c = t & 255, m = t >> 8;
        WtO[t] = tobf(WO[(size_t)c * DM + m]);
        return;
    }
    t -= NWO;
    if (t < 768) {
        bqkv[t] = (t < 256) ? bQ[t] : (t < 512 ? bK[t - 256] : bV[t - 512]);
        return;
    }
    t -= 768;
    if (t < 32 * 32) {               // tails: s in [2048, 2080)
        const int bh = t >> 5;
        const int s  = S_ + (t & 31);
        const int h  = bh & 15;
        short kb[16], vb[16];
        if (s < SK) {
            const int tt = s - S_;
#pragma unroll
            for (int e = 0; e < 16; ++e) {
                kb[e] = tobf(vKp[(size_t)tt * 256 + h * 16 + e]);
                vb[e] = tobf(vVp[(size_t)tt * 256 + h * 16 + e]);
            }
        } else {
#pragma unroll
            for (int e = 0; e < 16; ++e) { kb[e] = 0; vb[e] = 0; }
        }
        const int t5 = s >> 5;       // == 64
        short* kbase = Kb2 + ((size_t)bh * NT_ + t5) * 512 + (s & 31) * 8;
#pragma unroll
        for (int e = 0; e < 8; ++e)  { kbase[e] = kb[e]; kbase[256 + e] = kb[e + 8]; }
        short* vbase = Vt3 + ((size_t)bh * NT_ + t5) * 1024
                     + ((s >> 4) & 1) * 512 + ((s >> 3) & 1) * 8 + (s & 7);
#pragma unroll
        for (int dv = 0; dv < 16; ++dv) vbase[dv * 16] = vb[dv];
    }
}

// ---------------------------------------------------------------------------
// mm_qkv: R13 main loop (single-buffer, XCD remap) + LDS-TRANSPOSED epilogue:
//  acc -> fp32 LDS tile [128][65] -> re-partitioned threads apply bias+rotary
//  locally and emit coalesced short8 stores (8-16x fewer store instrs).
// ---------------------------------------------------------------------------
__global__ __launch_bounds__(256) void mm_qkv(
    const short* __restrict__ A, const short* __restrict__ Bt,
    const float* __restrict__ bias,
    short* __restrict__ Qb2, short* __restrict__ Kb2, short* __restrict__ Vt3)
{
    __shared__ float CtS[128][65];               // 33.3 KB; hosts As/Bs views
    short* As = (short*)&CtS[0][0];              // 16 KB
    short* Bs = (short*)&CtS[0][0] + 8192;       // 8 KB

    const int tid  = threadIdx.x;
    const int w    = tid >> 6;
    const int lane = tid & 63;
    const int wm   = w >> 1, wn = w & 1;
    const int g    = lane >> 4, c = lane & 15;

    const int linear = blockIdx.y * 12 + blockIdx.x;   // 0..383
    const int xcd  = linear & 7;
    const int jj2  = linear >> 3;                      // 0..47
    const int m0   = (xcd * 4 + jj2 / 12) * 128;
    const int n0   = (jj2 % 12) * 64;

    f32x4 acc[4][2];
#pragma unroll
    for (int i = 0; i < 4; ++i)
#pragma unroll
        for (int j = 0; j < 2; ++j) acc[i][j] = (f32x4){0.f, 0.f, 0.f, 0.f};

    const int lr = lane >> 3;
    const int lc = lane & 7;

    for (int k0 = 0; k0 < 768; k0 += 64) {
#pragma unroll
        for (int i = 0; i < 4; ++i) {
            const int ch  = i * 4 + w;
            const int row = ch * 8 + lr;
            const int scc = lc ^ (row & 7);
            gload_lds16(A + (size_t)(m0 + row) * 768 + k0 + scc * 8, As + ch * 512);
        }
#pragma unroll
        for (int i = 0; i < 2; ++i) {
            const int ch  = i * 4 + w;
            const int row = ch * 8 + lr;
            const int scc = lc ^ (row & 7);
            gload_lds16(Bt + (size_t)(n0 + row) * 768 + k0 + scc * 8, Bs + ch * 512);
        }
        __syncthreads();
#pragma unroll
        for (int kk = 0; kk < 64; kk += 32) {
            short8 af[4], bf[2];
#pragma unroll
            for (int i = 0; i < 4; ++i) {
                const int row = wm * 64 + i * 16 + c;
                const int sc  = ((kk >> 3) + g) ^ (row & 7);
                af[i] = *(const short8*)(As + row * 64 + sc * 8);
            }
#pragma unroll
            for (int j = 0; j < 2; ++j) {
                const int row = wn * 32 + j * 16 + c;
                const int sc  = ((kk >> 3) + g) ^ (row & 7);
                bf[j] = *(const short8*)(Bs + row * 64 + sc * 8);
            }
#pragma unroll
            for (int i = 0; i < 4; ++i)
#pragma unroll
                for (int j = 0; j < 2; ++j)
                    acc[i][j] = __builtin_amdgcn_mfma_f32_16x16x32_bf16(
                        af[i], bf[j], acc[i][j], 0, 0, 0);
        }
        __syncthreads();
    }

    // ---- LDS-transposed epilogue ----
#pragma unroll
    for (int i = 0; i < 4; ++i)
#pragma unroll
        for (int j = 0; j < 2; ++j)
#pragma unroll
            for (int r = 0; r < 4; ++r)
                CtS[wm * 64 + i * 16 + 4 * g + r][wn * 32 + j * 16 + c] = acc[i][j][r];
    __syncthreads();

    const int b = m0 >> 11;
    if (n0 < 512) {
        const int isQ   = n0 < 256;
        const int hbase = (n0 & 255) >> 4;
#pragma unroll
        for (int it = 0; it < 2; ++it) {
            const int idx  = it * 256 + tid;      // 0..511
            const int srow = idx & 127;
            const int g16  = idx >> 7;            // 0..3
            const int s    = (m0 + srow) & 2047;
            const int bh   = b * 16 + hbase + g16;
            float v[16];
#pragma unroll
            for (int e = 0; e < 16; ++e)
                v[e] = CtS[srow][g16 * 16 + e] + bias[n0 + g16 * 16 + e];
            union { short s[16]; short8 v8[2]; } u;
#pragma unroll
            for (int e = 0; e < 8; ++e) {
                const float invf = __builtin_amdgcn_exp2f(-(float)e * L2B8);
                float sn, cs;
                __sincosf((float)s * invf, &sn, &cs);
                float o0 = v[e] * cs - v[e + 8] * sn;
                float o1 = v[e + 8] * cs + v[e] * sn;
                if (isQ) { o0 *= QSCALE; o1 *= QSCALE; }
                u.s[e] = tobf(o0); u.s[e + 8] = tobf(o1);
            }
            short* dst = (isQ ? Qb2 + ((size_t)bh * 64 + (s >> 5)) * 512
                              : Kb2 + ((size_t)bh * NT_ + (s >> 5)) * 512)
                       + (s & 31) * 8;
            *(short8*)dst         = u.v8[0];
            *(short8*)(dst + 256) = u.v8[1];
        }
    } else {
        const int hbase = (n0 - 512) >> 4;
#pragma unroll
        for (int it = 0; it < 2; ++it) {
            const int idx = it * 256 + tid;       // 0..511
            const int dvl = idx & 63;             // tile col
            const int rg  = idx >> 6;             // 0..7 row group
            const int s0  = (m0 + rg * 16) & 2047;
            const int bh  = b * 16 + hbase + (dvl >> 4);
            const float bv = bias[n0 + dvl];
            union { short s[16]; short8 v8[2]; } u;
#pragma unroll
            for (int k = 0; k < 16; ++k)
                u.s[k] = tobf(CtS[rg * 16 + k][dvl] + bv);
            short* dst = Vt3 + ((size_t)bh * NT_ + (s0 >> 5)) * 1024
                       + ((s0 >> 4) & 1) * 512 + (dvl & 15) * 16;
            *(short8*)dst       = u.v8[0];
            *(short8*)(dst + 8) = u.v8[1];
        }
    }
}

// ---------------------------------------------------------------------------
// mm_out: out[4096][768] = Zb[4096][256] * WtO^T + bO  (fp32 out), XCD remap.
// (R13-exact)
// ---------------------------------------------------------------------------
__global__ __launch_bounds__(256) void mm_out(
    const short* __restrict__ A, const short* __restrict__ Bt,
    const float* __restrict__ bias, float* __restrict__ Cout)
{
    __shared__ short As[128 * 64];
    __shared__ short Bs[64 * 64];

    const int tid  = threadIdx.x;
    const int w    = tid >> 6;
    const int lane = tid & 63;
    const int wm   = w >> 1, wn = w & 1;
    const int g    = lane >> 4, c = lane & 15;

    const int linear = blockIdx.y * 12 + blockIdx.x;
    const int xcd  = linear & 7;
    const int jj2  = linear >> 3;
    const int m0   = (xcd * 4 + jj2 / 12) * 128;
    const int n0   = (jj2 % 12) * 64;

    f32x4 acc[4][2];
#pragma unroll
    for (int i = 0; i < 4; ++i)
#pragma unroll
        for (int j = 0; j < 2; ++j) acc[i][j] = (f32x4){0.f, 0.f, 0.f, 0.f};

    const int lr = lane >> 3;
    const int lc = lane & 7;

    for (int k0 = 0; k0 < 256; k0 += 64) {
#pragma unroll
        for (int i = 0; i < 4; ++i) {
            const int ch  = i * 4 + w;
            const int row = ch * 8 + lr;
            const int scc = lc ^ (row & 7);
            gload_lds16(A + (size_t)(m0 + row) * 256 + k0 + scc * 8, As + ch * 512);
        }
#pragma unroll
        for (int i = 0; i < 2; ++i) {
            const int ch  = i * 4 + w;
            const int row = ch * 8 + lr;
            const int scc = lc ^ (row & 7);
            gload_lds16(Bt + (size_t)(n0 + row) * 256 + k0 + scc * 8, Bs + ch * 512);
        }
        __syncthreads();
#pragma unroll
        for (int kk = 0; kk < 64; kk += 32) {
            short8 af[4], bf[2];
#pragma unroll
            for (int i = 0; i < 4; ++i) {
                const int row = wm * 64 + i * 16 + c;
                const int sc  = ((kk >> 3) + g) ^ (row & 7);
                af[i] = *(const short8*)(As + row * 64 + sc * 8);
            }
#pragma unroll
            for (int j = 0; j < 2; ++j) {
                const int row = wn * 32 + j * 16 + c;
                const int sc  = ((kk >> 3) + g) ^ (row & 7);
                bf[j] = *(const short8*)(Bs + row * 64 + sc * 8);
            }
#pragma unroll
            for (int i = 0; i < 4; ++i)
#pragma unroll
                for (int j = 0; j < 2; ++j)
                    acc[i][j] = __builtin_amdgcn_mfma_f32_16x16x32_bf16(
                        af[i], bf[j], acc[i][j], 0, 0, 0);
        }
        __syncthreads();
    }
#pragma unroll
    for (int i = 0; i < 4; ++i)
#pragma unroll
        for (int j = 0; j < 2; ++j) {
            const int col = n0 + wn * 32 + j * 16 + c;
            const float bv = bias[col];
#pragma unroll
            for (int r = 0; r < 4; ++r) {
                const int row = m0 + wm * 64 + i * 16 + 4 * g + r;
                Cout[(size_t)row * DM + col] = acc[i][j][r] + bv;
            }
        }
}

// ---------------------------------------------------------------------------
// attn_split: R13-exact (paired key-tile loop, 1-deep prefetch, XCD-affine
//  bh mapping, setprio around MFMA clusters). Proven 60.1 us config.
// ---------------------------------------------------------------------------
__global__ __launch_bounds__(256) void attn_split(
    const short* __restrict__ Qb2, const short* __restrict__ Kb2,
    const short* __restrict__ Vt3, unsigned* __restrict__ PartA,
    float* __restrict__ PartL)
{
    const int w    = threadIdx.x >> 6;
    const int lane = threadIdx.x & 63;
    const int blk  = blockIdx.x;            // 0..1311
    const int xcd  = blk & 7;
    const int j    = blk >> 3;              // 0..163
    const int bhl  = j / 41;                // 0..3
    const int slot = j - bhl * 41;          // 0..40
    const int bh   = xcd * 4 + bhl;
    const int r    = slot * 4 + w;          // 0..163
    int qt, sp;
    if (r < 49)       { sp = 1; qt = 15 + r; }
    else if (r < 82)  { sp = 2; qt = 31 + (r - 49); }
    else if (r < 99)  { sp = 3; qt = 47 + (r - 82); }
    else if (r == 99) { sp = 4; qt = 63; }
    else              { sp = 0; qt = 163 - r; }

    const int nt   = qt + 2;
    const int t0   = sp * TSPLIT;
    const int tend = min(t0 + TSPLIT, nt);

    const int hi = lane >> 5;
    const int qc = lane & 31;
    const int q0 = qt * 32;

    const f32x16 zero16 = {0,0,0,0,0,0,0,0,0,0,0,0,0,0,0,0};

    short8 qf = *(const short8*)(Qb2 + ((size_t)bh * 64 + qt) * 512 + lane * 8);

    f32x16 acc = zero16;
    float lsum = 0.f;

    const short* kbase = Kb2 + (size_t)bh * NT_ * 512 + lane * 8;
    const short* vbase = Vt3 + (size_t)bh * NT_ * 1024 + (lane & 15) * 16 + hi * 8;
    const int qv16  = q0 + qc + 16;
    const int tmask = (q0 + 17) >> 5;      // first tile index needing mask

#define LK(tt)  (*(const short8*)(kbase + (size_t)(tt) * 512))
#define LVA(tt) (*(const short8*)(vbase + (size_t)(tt) * 1024))
#define LVB(tt) (*(const short8*)(vbase + (size_t)(tt) * 1024 + 512))

#define SOFTMAX_TILE(S, tt, B1, B2)                                          \
    {                                                                        \
        if ((tt) >= tmask) {                                                 \
            const int kt_ = (tt) * 32;                                       \
            _Pragma("unroll")                                                \
            for (int rr = 0; rr < 16; ++rr) {                                \
                const int key = kt_ + (rr & 3) + 8 * (rr >> 2) + 4 * hi;     \
                S[rr] = (key <= qv16) ? S[rr] : -INFINITY;                   \
            }                                                                \
        }                                                                    \
        unsigned pk[8];                                                      \
        _Pragma("unroll")                                                    \
        for (int jj = 0; jj < 8; ++jj) {                                     \
            const float p0 = __builtin_amdgcn_exp2f(S[2 * jj]);              \
            const float p1 = __builtin_amdgcn_exp2f(S[2 * jj + 1]);          \
            lsum += p0 + p1;                                                 \
            asm("v_cvt_pk_bf16_f32 %0, %1, %2" : "=v"(pk[jj]) : "v"(p0), "v"(p1)); \
        }                                                                    \
        unsigned a0 = pk[0], a2 = pk[2], a1 = pk[1], a3 = pk[3];             \
        unsigned a4 = pk[4], a6 = pk[6], a5 = pk[5], a7 = pk[7];             \
        asm("v_permlane32_swap_b32 %0, %1" : "+v"(a0), "+v"(a2));            \
        asm("v_permlane32_swap_b32 %0, %1" : "+v"(a1), "+v"(a3));            \
        asm("v_permlane32_swap_b32 %0, %1" : "+v"(a4), "+v"(a6));            \
        asm("v_permlane32_swap_b32 %0, %1" : "+v"(a5), "+v"(a7));            \
        B1.u[0] = a0; B1.u[1] = a1; B1.u[2] = a2; B1.u[3] = a3;              \
        B2.u[0] = a4; B2.u[1] = a5; B2.u[2] = a6; B2.u[3] = a7;              \
    }

    const int npair_end = t0 + ((tend - t0) & ~1);

    if (t0 < npair_end) {
        short8 kfA = LK(t0),     vaA = LVA(t0),     vvA = LVB(t0);
        short8 kfB = LK(t0 + 1), vaB = LVA(t0 + 1), vvB = LVB(t0 + 1);

        for (int t = t0; t < npair_end; t += 2) {
            short8 kfA_n = kfA, vaA_n = vaA, vvA_n = vvA;
            short8 kfB_n = kfB, vaB_n = vaB, vvB_n = vvB;
            if (t + 2 < npair_end) {
                kfA_n = LK(t + 2); vaA_n = LVA(t + 2); vvA_n = LVB(t + 2);
                kfB_n = LK(t + 3); vaB_n = LVA(t + 3); vvB_n = LVB(t + 3);
            }

            __builtin_amdgcn_s_setprio(1);
            f32x16 S0 = __builtin_amdgcn_mfma_f32_32x32x16_bf16(kfA, qf, zero16, 0, 0, 0);
            f32x16 S1 = __builtin_amdgcn_mfma_f32_32x32x16_bf16(kfB, qf, zero16, 0, 0, 0);
            __builtin_amdgcn_s_setprio(0);

            union { unsigned u[4]; short8 v; } b1A, b2A, b1B, b2B;
            SOFTMAX_TILE(S0, t,     b1A, b2A);
            SOFTMAX_TILE(S1, t + 1, b1B, b2B);

            __builtin_amdgcn_s_setprio(1);
            acc = __builtin_amdgcn_mfma_f32_32x32x16_bf16(vaA, b1A.v, acc, 0, 0, 0);
            acc = __builtin_amdgcn_mfma_f32_32x32x16_bf16(vvA, b2A.v, acc, 0, 0, 0);
            acc = __builtin_amdgcn_mfma_f32_32x32x16_bf16(vaB, b1B.v, acc, 0, 0, 0);
            acc = __builtin_amdgcn_mfma_f32_32x32x16_bf16(vvB, b2B.v, acc, 0, 0, 0);
            __builtin_amdgcn_s_setprio(0);

            kfA = kfA_n; vaA = vaA_n; vvA = vvA_n;
            kfB = kfB_n; vaB = vaB_n; vvB = vvB_n;
        }
    }
    if (npair_end < tend) {                        // odd tail tile
        const int t = npair_end;
        short8 kf = LK(t), va = LVA(t), vv = LVB(t);
        f32x16 S0 = __builtin_amdgcn_mfma_f32_32x32x16_bf16(kf, qf, zero16, 0, 0, 0);
        union { unsigned u[4]; short8 v; } b1, b2;
        SOFTMAX_TILE(S0, t, b1, b2);
        acc = __builtin_amdgcn_mfma_f32_32x32x16_bf16(va, b1.v, acc, 0, 0, 0);
        acc = __builtin_amdgcn_mfma_f32_32x32x16_bf16(vv, b2.v, acc, 0, 0, 0);
    }

    uint4v pa;
    asm("v_cvt_pk_bf16_f32 %0, %1, %2" : "=v"(pa.x) : "v"(acc[0]), "v"(acc[1]));
    asm("v_cvt_pk_bf16_f32 %0, %1, %2" : "=v"(pa.y) : "v"(acc[2]), "v"(acc[3]));
    asm("v_cvt_pk_bf16_f32 %0, %1, %2" : "=v"(pa.z) : "v"(acc[4]), "v"(acc[5]));
    asm("v_cvt_pk_bf16_f32 %0, %1, %2" : "=v"(pa.w) : "v"(acc[6]), "v"(acc[7]));

    const int pidx = (bh * 64 + qt) * MAXSP + sp;
    *(uint4v*)(PartA + ((size_t)pidx * 64 + lane) * 4) = pa;

    lsum += __shfl_xor(lsum, 32);
    if (hi == 0) PartL[(size_t)pidx * 32 + qc] = lsum;
}

// ---------------------------------------------------------------------------
// attn_combine: wave per (bh,qt): sum <=MAXSP partials, normalize, write Z.
// ---------------------------------------------------------------------------
__global__ __launch_bounds__(256) void attn_combine(
    const unsigned* __restrict__ PartA, const float* __restrict__ PartL,
    short* __restrict__ Zb)
{
    const int w    = threadIdx.x >> 6;
    const int lane = threadIdx.x & 63;
    const int wid  = blockIdx.x * 4 + w;
    const int bh   = wid >> 6;
    const int qt   = wid & 63;
    const int hi   = lane >> 5;
    const int qc   = lane & 31;
    const int ns   = (qt + 2 + TSPLIT - 1) / TSPLIT;

    float a[8];
#pragma unroll
    for (int rr = 0; rr < 8; ++rr) a[rr] = 0.f;
    float lsum = 0.f;

    const int pbase = (bh * 64 + qt) * MAXSP;
    for (int sp = 0; sp < ns; ++sp) {
        uint4v pa = *(const uint4v*)(PartA + ((size_t)(pbase + sp) * 64 + lane) * 4);
        a[0] += frombf_lo(pa.x); a[1] += frombf_hi(pa.x);
        a[2] += frombf_lo(pa.y); a[3] += frombf_hi(pa.y);
        a[4] += frombf_lo(pa.z); a[5] += frombf_hi(pa.z);
        a[6] += frombf_lo(pa.w); a[7] += frombf_hi(pa.w);
        lsum += PartL[(size_t)(pbase + sp) * 32 + qc];
    }
    const float inv = 1.f / lsum;

    const int b = bh >> 4, h = bh & 15;
    const int q0 = qt * 32;
    short* zp = Zb + ((size_t)(b * S_ + q0 + qc)) * C_ + h * 16;
    unsigned o01, o23, o45, o67;
    {
        float a0 = a[0] * inv, a1 = a[1] * inv, a2 = a[2] * inv, a3 = a[3] * inv;
        float a4 = a[4] * inv, a5 = a[5] * inv, a6 = a[6] * inv, a7 = a[7] * inv;
        asm("v_cvt_pk_bf16_f32 %0, %1, %2" : "=v"(o01) : "v"(a0), "v"(a1));
        asm("v_cvt_pk_bf16_f32 %0, %1, %2" : "=v"(o23) : "v"(a2), "v"(a3));
        asm("v_cvt_pk_bf16_f32 %0, %1, %2" : "=v"(o45) : "v"(a4), "v"(a5));
        asm("v_cvt_pk_bf16_f32 %0, %1, %2" : "=v"(o67) : "v"(a6), "v"(a7));
    }
    *(unsigned*)(zp + 4 * hi)         = o01;
    *(unsigned*)(zp + 4 * hi + 2)     = o23;
    *(unsigned*)(zp + 8 + 4 * hi)     = o45;
    *(unsigned*)(zp + 8 + 4 * hi + 2) = o67;
}

extern "C" void kernel_launch(void* const* d_in, const int* in_sizes, int n_in,
                              void* d_out, int out_size, void* d_ws, size_t ws_size,
                              hipStream_t stream)
{
    const float* resid = (const float*)d_in[0];
    const float* WQ = (const float*)d_in[1];
    const float* WK = (const float*)d_in[2];
    const float* WV = (const float*)d_in[3];
    const float* WO = (const float*)d_in[4];
    const float* bQ = (const float*)d_in[5];
    const float* bK = (const float*)d_in[6];
    const float* bV = (const float*)d_in[7];
    const float* bO = (const float*)d_in[8];
    const float* vK = (const float*)d_in[9];
    const float* vV = (const float*)d_in[10];
    float* out = (float*)d_out;
    float* ws  = (float*)d_ws;

    short* Zb   = (short*)ws;                       // 4096*256 bf16
    float* bqkv = ws + 3145728;                     // 768 f32
    short* Ab   = (short*)(ws + 3145728 + 768);     // 3,145,728 bf16
    short* Wqt  = Ab + 3145728;                     // 589,824
    short* WtO  = Wqt + 589824;                     // 196,608
    short* Qb2  = WtO + 196608;                     // 32*64*512  = 1,048,576
    short* Kb2  = Qb2 + 1048576;                    // 32*65*512  = 1,064,960
    short* Vt3  = Kb2 + 1064960;                    // 32*65*1024 = 2,129,920
    unsigned* PartA = (unsigned*)(Vt3 + 2129920);   // 10240*64*4 u32
    float*    PartL = (float*)(PartA + 2621440);    // 10240*32 f32

    const int conv_total = NRES + NWQ + NWO + 768 + 1024;
    conv_all<<<dim3((conv_total + 255) / 256), 256, 0, stream>>>(
        resid, WQ, WK, WV, WO, bQ, bK, bV, vK, vV,
        Ab, Wqt, WtO, bqkv, Kb2, Vt3);
    mm_qkv<<<dim3(12, 32), 256, 0, stream>>>(Ab, Wqt, bqkv, Qb2, Kb2, Vt3);
    attn_split<<<dim3(32 * NACT / 4), 256, 0, stream>>>(Qb2, Kb2, Vt3, PartA, PartL);
    attn_combine<<<dim3(512), 256, 0, stream>>>(PartA, PartL, Zb);
    mm_out<<<dim3(12, 32), 256, 0, stream>>>(Zb, WtO, bO, out);
}

// Round 17
// 55.415 us; speedup vs baseline: 1.1378x; 1.0504x over previous
//
#include <hip/hip_runtime.h>
#include <hip/hip_bf16.h>
#include <math.h>

// Problem constants
#define B_   2
#define S_   2048
#define DM   768
#define H_   16      // N_QK
#define C_   256     // N_OV
#define VKV_ 16
#define SK   2064    // S_ + VKV_
#define SKP  2080
#define NT_  65      // key tiles per bh

#define TSPLIT 16
#define MAXSP  5     // ceil(65/16)
#define NACT   164   // active (qt,sp) pairs per bh

typedef __attribute__((ext_vector_type(8))) short short8;    // 8 bf16
typedef __attribute__((ext_vector_type(4))) short short4v;
typedef __attribute__((ext_vector_type(4))) float f32x4;
typedef __attribute__((ext_vector_type(16))) float f32x16;
typedef __attribute__((ext_vector_type(4))) unsigned uint4v;

// log2(e) / SCALE folded into Q so p = exp2(s)
#define QSCALE 0.360673760222240851f
// log2(10000)/8
#define L2B8   1.6609640474436811f

__device__ __forceinline__ short tobf(float f) {
    union { float f; unsigned u; } x; x.f = f;
    unsigned r = x.u + 0x7FFFu + ((x.u >> 16) & 1u);   // RNE
    return (short)(r >> 16);
}
__device__ __forceinline__ float frombf_lo(unsigned u) {
    union { unsigned u; float f; } x; x.u = u << 16; return x.f;
}
__device__ __forceinline__ float frombf_hi(unsigned u) {
    union { unsigned u; float f; } x; x.u = u & 0xFFFF0000u; return x.f;
}

__device__ __forceinline__ void gload_lds16(const short* g, short* l) {
    __builtin_amdgcn_global_load_lds(
        (const __attribute__((address_space(1))) unsigned int*)g,
        (__attribute__((address_space(3))) unsigned int*)l, 16, 0, 0);
}

// ---------------------------------------------------------------------------
// conv_all: resid->bf16, weights pack (coalesced Q/K remap), bias, K/V tails.
// ---------------------------------------------------------------------------
#define NRES (4096*768/4)
#define NWQ  (768*768)
#define NWO  (768*256)
__global__ __launch_bounds__(256) void conv_all(
    const float* __restrict__ resid,
    const float* __restrict__ WQ, const float* __restrict__ WK,
    const float* __restrict__ WV, const float* __restrict__ WO,
    const float* __restrict__ bQ, const float* __restrict__ bK,
    const float* __restrict__ bV,
    const float* __restrict__ vKp, const float* __restrict__ vVp,
    short* __restrict__ Ab, short* __restrict__ Wqkv_t,
    short* __restrict__ WtO, float* __restrict__ bqkv,
    short* __restrict__ Kb2, short* __restrict__ Vt3)
{
    int t = blockIdx.x * 256 + threadIdx.x;
    if (t < NRES) {
        float4 v = *(const float4*)(resid + (size_t)t * 4);
        short4v o = { tobf(v.x), tobf(v.y), tobf(v.z), tobf(v.w) };
        *(short4v*)(Ab + (size_t)t * 4) = o;
        return;
    }
    t -= NRES;
    if (t < NWQ) {
        int cc, d;
        if (t < 512 * 768) {            // Q,K: remap so reads are contiguous
            const int e    = t & 15;
            const int rest = t >> 4;
            d  = rest % 768;
            cc = (rest / 768) * 16 + e; // 0..511
        } else { cc = t / 768; d = t % 768; }
        float w;
        if (cc < 256)      w = WQ[((size_t)(cc >> 4) * DM + d) * 16 + (cc & 15)];
        else if (cc < 512) w = WK[((size_t)((cc - 256) >> 4) * DM + d) * 16 + (cc & 15)];
        else               w = WV[(size_t)(cc - 512) * DM + d];
        Wqkv_t[(size_t)cc * 768 + d] = tobf(w);
        return;
    }
    t -= NWQ;
    if (t < NWO) {
        int c = t & 255, m = t >> 8;
        WtO[t] = tobf(WO[(size_t)c * DM + m]);
        return;
    }
    t -= NWO;
    if (t < 768) {
        bqkv[t] = (t < 256) ? bQ[t] : (t < 512 ? bK[t - 256] : bV[t - 512]);
        return;
    }
    t -= 768;
    if (t < 32 * 32) {               // tails: s in [2048, 2080)
        const int bh = t >> 5;
        const int s  = S_ + (t & 31);
        const int h  = bh & 15;
        short kb[16], vb[16];
        if (s < SK) {
            const int tt = s - S_;
#pragma unroll
            for (int e = 0; e < 16; ++e) {
                kb[e] = tobf(vKp[(size_t)tt * 256 + h * 16 + e]);
                vb[e] = tobf(vVp[(size_t)tt * 256 + h * 16 + e]);
            }
        } else {
#pragma unroll
            for (int e = 0; e < 16; ++e) { kb[e] = 0; vb[e] = 0; }
        }
        const int t5 = s >> 5;       // == 64
        short* kbase = Kb2 + ((size_t)bh * NT_ + t5) * 512 + (s & 31) * 8;
#pragma unroll
        for (int e = 0; e < 8; ++e)  { kbase[e] = kb[e]; kbase[256 + e] = kb[e + 8]; }
        short* vbase = Vt3 + ((size_t)bh * NT_ + t5) * 1024
                     + ((s >> 4) & 1) * 512 + ((s >> 3) & 1) * 8 + (s & 7);
#pragma unroll
        for (int dv = 0; dv < 16; ++dv) vbase[dv * 16] = vb[dv];
    }
}

// ---------------------------------------------------------------------------
// mm_qkv: 64x64 tiles (768 blocks = 3/CU, all CUs busy), XCD remap,
//  LDS-transposed rotary/scatter epilogue (coalesced short8 stores).
// ---------------------------------------------------------------------------
__global__ __launch_bounds__(256) void mm_qkv(
    const short* __restrict__ A, const short* __restrict__ Bt,
    const float* __restrict__ bias,
    short* __restrict__ Qb2, short* __restrict__ Kb2, short* __restrict__ Vt3)
{
    __shared__ float CtS[64][65];                // 16.64 KB; hosts As/Bs views
    short* As = (short*)&CtS[0][0];              // 8 KB (4096 shorts)
    short* Bs = As + 4096;                       // 8 KB

    const int tid  = threadIdx.x;
    const int w    = tid >> 6;
    const int lane = tid & 63;
    const int wm   = w >> 1, wn = w & 1;
    const int g    = lane >> 4, c = lane & 15;

    const int linear = blockIdx.y * 12 + blockIdx.x;   // 0..767
    const int xcd  = linear & 7;
    const int jj2  = linear >> 3;                      // 0..95
    const int m0   = (xcd * 8 + jj2 / 12) * 64;
    const int n0   = (jj2 % 12) * 64;

    f32x4 acc[2][2];
#pragma unroll
    for (int i = 0; i < 2; ++i)
#pragma unroll
        for (int j = 0; j < 2; ++j) acc[i][j] = (f32x4){0.f, 0.f, 0.f, 0.f};

    const int lr = lane >> 3;
    const int lc = lane & 7;

    for (int k0 = 0; k0 < 768; k0 += 64) {
#pragma unroll
        for (int i = 0; i < 2; ++i) {              // A chunks: w, w+4
            const int ch  = i * 4 + w;
            const int row = ch * 8 + lr;
            const int scc = lc ^ (row & 7);
            gload_lds16(A + (size_t)(m0 + row) * 768 + k0 + scc * 8, As + ch * 512);
        }
#pragma unroll
        for (int i = 0; i < 2; ++i) {              // B chunks: w, w+4
            const int ch  = i * 4 + w;
            const int row = ch * 8 + lr;
            const int scc = lc ^ (row & 7);
            gload_lds16(Bt + (size_t)(n0 + row) * 768 + k0 + scc * 8, Bs + ch * 512);
        }
        __syncthreads();
#pragma unroll
        for (int kk = 0; kk < 64; kk += 32) {
            short8 af[2], bf[2];
#pragma unroll
            for (int i = 0; i < 2; ++i) {
                const int row = wm * 32 + i * 16 + c;
                const int sc  = ((kk >> 3) + g) ^ (row & 7);
                af[i] = *(const short8*)(As + row * 64 + sc * 8);
            }
#pragma unroll
            for (int j = 0; j < 2; ++j) {
                const int row = wn * 32 + j * 16 + c;
                const int sc  = ((kk >> 3) + g) ^ (row & 7);
                bf[j] = *(const short8*)(Bs + row * 64 + sc * 8);
            }
#pragma unroll
            for (int i = 0; i < 2; ++i)
#pragma unroll
                for (int j = 0; j < 2; ++j)
                    acc[i][j] = __builtin_amdgcn_mfma_f32_16x16x32_bf16(
                        af[i], bf[j], acc[i][j], 0, 0, 0);
        }
        __syncthreads();
    }

    // ---- LDS-transposed epilogue ----
#pragma unroll
    for (int i = 0; i < 2; ++i)
#pragma unroll
        for (int j = 0; j < 2; ++j)
#pragma unroll
            for (int r = 0; r < 4; ++r)
                CtS[wm * 32 + i * 16 + 4 * g + r][wn * 32 + j * 16 + c] = acc[i][j][r];
    __syncthreads();

    const int b = m0 >> 11;
    if (n0 < 512) {
        const int isQ   = n0 < 256;
        const int hbase = (n0 & 255) >> 4;
        const int srow = tid & 63;
        const int g16  = tid >> 6;                // 0..3
        const int s    = (m0 + srow) & 2047;
        const int bh   = b * 16 + hbase + g16;
        float v[16];
#pragma unroll
        for (int e = 0; e < 16; ++e)
            v[e] = CtS[srow][g16 * 16 + e] + bias[n0 + g16 * 16 + e];
        union { short s[16]; short8 v8[2]; } u;
#pragma unroll
        for (int e = 0; e < 8; ++e) {
            const float invf = __builtin_amdgcn_exp2f(-(float)e * L2B8);
            float sn, cs;
            __sincosf((float)s * invf, &sn, &cs);
            float o0 = v[e] * cs - v[e + 8] * sn;
            float o1 = v[e + 8] * cs + v[e] * sn;
            if (isQ) { o0 *= QSCALE; o1 *= QSCALE; }
            u.s[e] = tobf(o0); u.s[e + 8] = tobf(o1);
        }
        short* dst = (isQ ? Qb2 + ((size_t)bh * 64 + (s >> 5)) * 512
                          : Kb2 + ((size_t)bh * NT_ + (s >> 5)) * 512)
                   + (s & 31) * 8;
        *(short8*)dst         = u.v8[0];
        *(short8*)(dst + 256) = u.v8[1];
    } else {
        const int hbase = (n0 - 512) >> 4;
        const int dvl = tid & 63;
        const int rg  = tid >> 6;                 // 0..3
        const int s0  = (m0 + rg * 16) & 2047;
        const int bh  = b * 16 + hbase + (dvl >> 4);
        const float bv = bias[n0 + dvl];
        union { short s[16]; short8 v8[2]; } u;
#pragma unroll
        for (int k = 0; k < 16; ++k)
            u.s[k] = tobf(CtS[rg * 16 + k][dvl] + bv);
        short* dst = Vt3 + ((size_t)bh * NT_ + (s0 >> 5)) * 1024
                   + ((s0 >> 4) & 1) * 512 + (dvl & 15) * 16;
        *(short8*)dst       = u.v8[0];
        *(short8*)(dst + 8) = u.v8[1];
    }
}

// ---------------------------------------------------------------------------
// mm_out: 64x64 tiles (768 blocks), XCD remap, fp32 out.
// ---------------------------------------------------------------------------
__global__ __launch_bounds__(256) void mm_out(
    const short* __restrict__ A, const short* __restrict__ Bt,
    const float* __restrict__ bias, float* __restrict__ Cout)
{
    __shared__ short As[4096];
    __shared__ short Bs[4096];

    const int tid  = threadIdx.x;
    const int w    = tid >> 6;
    const int lane = tid & 63;
    const int wm   = w >> 1, wn = w & 1;
    const int g    = lane >> 4, c = lane & 15;

    const int linear = blockIdx.y * 12 + blockIdx.x;   // 0..767
    const int xcd  = linear & 7;
    const int jj2  = linear >> 3;
    const int m0   = (xcd * 8 + jj2 / 12) * 64;
    const int n0   = (jj2 % 12) * 64;

    f32x4 acc[2][2];
#pragma unroll
    for (int i = 0; i < 2; ++i)
#pragma unroll
        for (int j = 0; j < 2; ++j) acc[i][j] = (f32x4){0.f, 0.f, 0.f, 0.f};

    const int lr = lane >> 3;
    const int lc = lane & 7;

    for (int k0 = 0; k0 < 256; k0 += 64) {
#pragma unroll
        for (int i = 0; i < 2; ++i) {
            const int ch  = i * 4 + w;
            const int row = ch * 8 + lr;
            const int scc = lc ^ (row & 7);
            gload_lds16(A + (size_t)(m0 + row) * 256 + k0 + scc * 8, As + ch * 512);
        }
#pragma unroll
        for (int i = 0; i < 2; ++i) {
            const int ch  = i * 4 + w;
            const int row = ch * 8 + lr;
            const int scc = lc ^ (row & 7);
            gload_lds16(Bt + (size_t)(n0 + row) * 256 + k0 + scc * 8, Bs + ch * 512);
        }
        __syncthreads();
#pragma unroll
        for (int kk = 0; kk < 64; kk += 32) {
            short8 af[2], bf[2];
#pragma unroll
            for (int i = 0; i < 2; ++i) {
                const int row = wm * 32 + i * 16 + c;
                const int sc  = ((kk >> 3) + g) ^ (row & 7);
                af[i] = *(const short8*)(As + row * 64 + sc * 8);
            }
#pragma unroll
            for (int j = 0; j < 2; ++j) {
                const int row = wn * 32 + j * 16 + c;
                const int sc  = ((kk >> 3) + g) ^ (row & 7);
                bf[j] = *(const short8*)(Bs + row * 64 + sc * 8);
            }
#pragma unroll
            for (int i = 0; i < 2; ++i)
#pragma unroll
                for (int j = 0; j < 2; ++j)
                    acc[i][j] = __builtin_amdgcn_mfma_f32_16x16x32_bf16(
                        af[i], bf[j], acc[i][j], 0, 0, 0);
        }
        __syncthreads();
    }
#pragma unroll
    for (int i = 0; i < 2; ++i)
#pragma unroll
        for (int j = 0; j < 2; ++j) {
            const int col = n0 + wn * 32 + j * 16 + c;
            const float bv = bias[col];
#pragma unroll
            for (int r = 0; r < 4; ++r) {
                const int row = m0 + wm * 32 + i * 16 + 4 * g + r;
                Cout[(size_t)row * DM + col] = acc[i][j][r] + bv;
            }
        }
}

// ---------------------------------------------------------------------------
// attn_split: R13-exact loop + DIRECT-Z write for single-split waves
//  (sp==0 && qt<=14: nt<=TSPLIT, no partials needed -> skip PartA round trip).
// ---------------------------------------------------------------------------
__global__ __launch_bounds__(256) void attn_split(
    const short* __restrict__ Qb2, const short* __restrict__ Kb2,
    const short* __restrict__ Vt3, unsigned* __restrict__ PartA,
    float* __restrict__ PartL, short* __restrict__ Zb)
{
    const int w    = threadIdx.x >> 6;
    const int lane = threadIdx.x & 63;
    const int blk  = blockIdx.x;            // 0..1311
    const int xcd  = blk & 7;
    const int j    = blk >> 3;              // 0..163
    const int bhl  = j / 41;                // 0..3
    const int slot = j - bhl * 41;          // 0..40
    const int bh   = xcd * 4 + bhl;
    const int r    = slot * 4 + w;          // 0..163
    int qt, sp;
    if (r < 49)       { sp = 1; qt = 15 + r; }
    else if (r < 82)  { sp = 2; qt = 31 + (r - 49); }
    else if (r < 99)  { sp = 3; qt = 47 + (r - 82); }
    else if (r == 99) { sp = 4; qt = 63; }
    else              { sp = 0; qt = 163 - r; }

    const int nt   = qt + 2;
    const int t0   = sp * TSPLIT;
    const int tend = min(t0 + TSPLIT, nt);

    const int hi = lane >> 5;
    const int qc = lane & 31;
    const int q0 = qt * 32;

    const f32x16 zero16 = {0,0,0,0,0,0,0,0,0,0,0,0,0,0,0,0};

    short8 qf = *(const short8*)(Qb2 + ((size_t)bh * 64 + qt) * 512 + lane * 8);

    f32x16 acc = zero16;
    float lsum = 0.f;

    const short* kbase = Kb2 + (size_t)bh * NT_ * 512 + lane * 8;
    const short* vbase = Vt3 + (size_t)bh * NT_ * 1024 + (lane & 15) * 16 + hi * 8;
    const int qv16  = q0 + qc + 16;
    const int tmask = (q0 + 17) >> 5;      // first tile index needing mask

#define LK(tt)  (*(const short8*)(kbase + (size_t)(tt) * 512))
#define LVA(tt) (*(const short8*)(vbase + (size_t)(tt) * 1024))
#define LVB(tt) (*(const short8*)(vbase + (size_t)(tt) * 1024 + 512))

#define SOFTMAX_TILE(S, tt, B1, B2)                                          \
    {                                                                        \
        if ((tt) >= tmask) {                                                 \
            const int kt_ = (tt) * 32;                                       \
            _Pragma("unroll")                                                \
            for (int rr = 0; rr < 16; ++rr) {                                \
                const int key = kt_ + (rr & 3) + 8 * (rr >> 2) + 4 * hi;     \
                S[rr] = (key <= qv16) ? S[rr] : -INFINITY;                   \
            }                                                                \
        }                                                                    \
        unsigned pk[8];                                                      \
        _Pragma("unroll")                                                    \
        for (int jj = 0; jj < 8; ++jj) {                                     \
            const float p0 = __builtin_amdgcn_exp2f(S[2 * jj]);              \
            const float p1 = __builtin_amdgcn_exp2f(S[2 * jj + 1]);          \
            lsum += p0 + p1;                                                 \
            asm("v_cvt_pk_bf16_f32 %0, %1, %2" : "=v"(pk[jj]) : "v"(p0), "v"(p1)); \
        }                                                                    \
        unsigned a0 = pk[0], a2 = pk[2], a1 = pk[1], a3 = pk[3];             \
        unsigned a4 = pk[4], a6 = pk[6], a5 = pk[5], a7 = pk[7];             \
        asm("v_permlane32_swap_b32 %0, %1" : "+v"(a0), "+v"(a2));            \
        asm("v_permlane32_swap_b32 %0, %1" : "+v"(a1), "+v"(a3));            \
        asm("v_permlane32_swap_b32 %0, %1" : "+v"(a4), "+v"(a6));            \
        asm("v_permlane32_swap_b32 %0, %1" : "+v"(a5), "+v"(a7));            \
        B1.u[0] = a0; B1.u[1] = a1; B1.u[2] = a2; B1.u[3] = a3;              \
        B2.u[0] = a4; B2.u[1] = a5; B2.u[2] = a6; B2.u[3] = a7;              \
    }

    const int npair_end = t0 + ((tend - t0) & ~1);

    if (t0 < npair_end) {
        short8 kfA = LK(t0),     vaA = LVA(t0),     vvA = LVB(t0);
        short8 kfB = LK(t0 + 1), vaB = LVA(t0 + 1), vvB = LVB(t0 + 1);

        for (int t = t0; t < npair_end; t += 2) {
            short8 kfA_n = kfA, vaA_n = vaA, vvA_n = vvA;
            short8 kfB_n = kfB, vaB_n = vaB, vvB_n = vvB;
            if (t + 2 < npair_end) {
                kfA_n = LK(t + 2); vaA_n = LVA(t + 2); vvA_n = LVB(t + 2);
                kfB_n = LK(t + 3); vaB_n = LVA(t + 3); vvB_n = LVB(t + 3);
            }

            __builtin_amdgcn_s_setprio(1);
            f32x16 S0 = __builtin_amdgcn_mfma_f32_32x32x16_bf16(kfA, qf, zero16, 0, 0, 0);
            f32x16 S1 = __builtin_amdgcn_mfma_f32_32x32x16_bf16(kfB, qf, zero16, 0, 0, 0);
            __builtin_amdgcn_s_setprio(0);

            union { unsigned u[4]; short8 v; } b1A, b2A, b1B, b2B;
            SOFTMAX_TILE(S0, t,     b1A, b2A);
            SOFTMAX_TILE(S1, t + 1, b1B, b2B);

            __builtin_amdgcn_s_setprio(1);
            acc = __builtin_amdgcn_mfma_f32_32x32x16_bf16(vaA, b1A.v, acc, 0, 0, 0);
            acc = __builtin_amdgcn_mfma_f32_32x32x16_bf16(vvA, b2A.v, acc, 0, 0, 0);
            acc = __builtin_amdgcn_mfma_f32_32x32x16_bf16(vaB, b1B.v, acc, 0, 0, 0);
            acc = __builtin_amdgcn_mfma_f32_32x32x16_bf16(vvB, b2B.v, acc, 0, 0, 0);
            __builtin_amdgcn_s_setprio(0);

            kfA = kfA_n; vaA = vaA_n; vvA = vvA_n;
            kfB = kfB_n; vaB = vaB_n; vvB = vvB_n;
        }
    }
    if (npair_end < tend) {                        // odd tail tile
        const int t = npair_end;
        short8 kf = LK(t), va = LVA(t), vv = LVB(t);
        f32x16 S0 = __builtin_amdgcn_mfma_f32_32x32x16_bf16(kf, qf, zero16, 0, 0, 0);
        union { unsigned u[4]; short8 v; } b1, b2;
        SOFTMAX_TILE(S0, t, b1, b2);
        acc = __builtin_amdgcn_mfma_f32_32x32x16_bf16(va, b1.v, acc, 0, 0, 0);
        acc = __builtin_amdgcn_mfma_f32_32x32x16_bf16(vv, b2.v, acc, 0, 0, 0);
    }

    lsum += __shfl_xor(lsum, 32);

    if (sp == 0 && qt <= 14) {
        // single-split wave: normalize and write Z directly (no partials)
        const float inv = 1.f / lsum;
        const int b = bh >> 4, h = bh & 15;
        short* zp = Zb + ((size_t)(b * S_ + q0 + qc)) * C_ + h * 16;
        unsigned o01, o23, o45, o67;
        float a0 = acc[0] * inv, a1 = acc[1] * inv, a2 = acc[2] * inv, a3 = acc[3] * inv;
        float a4 = acc[4] * inv, a5 = acc[5] * inv, a6 = acc[6] * inv, a7 = acc[7] * inv;
        asm("v_cvt_pk_bf16_f32 %0, %1, %2" : "=v"(o01) : "v"(a0), "v"(a1));
        asm("v_cvt_pk_bf16_f32 %0, %1, %2" : "=v"(o23) : "v"(a2), "v"(a3));
        asm("v_cvt_pk_bf16_f32 %0, %1, %2" : "=v"(o45) : "v"(a4), "v"(a5));
        asm("v_cvt_pk_bf16_f32 %0, %1, %2" : "=v"(o67) : "v"(a6), "v"(a7));
        *(unsigned*)(zp + 4 * hi)         = o01;
        *(unsigned*)(zp + 4 * hi + 2)     = o23;
        *(unsigned*)(zp + 8 + 4 * hi)     = o45;
        *(unsigned*)(zp + 8 + 4 * hi + 2) = o67;
        return;
    }

    uint4v pa;
    asm("v_cvt_pk_bf16_f32 %0, %1, %2" : "=v"(pa.x) : "v"(acc[0]), "v"(acc[1]));
    asm("v_cvt_pk_bf16_f32 %0, %1, %2" : "=v"(pa.y) : "v"(acc[2]), "v"(acc[3]));
    asm("v_cvt_pk_bf16_f32 %0, %1, %2" : "=v"(pa.z) : "v"(acc[4]), "v"(acc[5]));
    asm("v_cvt_pk_bf16_f32 %0, %1, %2" : "=v"(pa.w) : "v"(acc[6]), "v"(acc[7]));

    const int pidx = (bh * 64 + qt) * MAXSP + sp;
    *(uint4v*)(PartA + ((size_t)pidx * 64 + lane) * 4) = pa;
    if (hi == 0) PartL[(size_t)pidx * 32 + qc] = lsum;
}

// ---------------------------------------------------------------------------
// attn_combine: only qt >= 15 (multi-split); 392 blocks.
// ---------------------------------------------------------------------------
__global__ __launch_bounds__(256) void attn_combine(
    const unsigned* __restrict__ PartA, const float* __restrict__ PartL,
    short* __restrict__ Zb)
{
    const int w    = threadIdx.x >> 6;
    const int lane = threadIdx.x & 63;
    const int wid  = blockIdx.x * 4 + w;     // 0..1567
    const int bh   = wid / 49;
    const int qt   = 15 + (wid - bh * 49);
    const int hi   = lane >> 5;
    const int qc   = lane & 31;
    const int ns   = (qt + 2 + TSPLIT - 1) / TSPLIT;

    float a[8];
#pragma unroll
    for (int rr = 0; rr < 8; ++rr) a[rr] = 0.f;
    float lsum = 0.f;

    const int pbase = (bh * 64 + qt) * MAXSP;
    for (int sp = 0; sp < ns; ++sp) {
        uint4v pa = *(const uint4v*)(PartA + ((size_t)(pbase + sp) * 64 + lane) * 4);
        a[0] += frombf_lo(pa.x); a[1] += frombf_hi(pa.x);
        a[2] += frombf_lo(pa.y); a[3] += frombf_hi(pa.y);
        a[4] += frombf_lo(pa.z); a[5] += frombf_hi(pa.z);
        a[6] += frombf_lo(pa.w); a[7] += frombf_hi(pa.w);
        lsum += PartL[(size_t)(pbase + sp) * 32 + qc];
    }
    const float inv = 1.f / lsum;

    const int b = bh >> 4, h = bh & 15;
    const int q0 = qt * 32;
    short* zp = Zb + ((size_t)(b * S_ + q0 + qc)) * C_ + h * 16;
    unsigned o01, o23, o45, o67;
    {
        float a0 = a[0] * inv, a1 = a[1] * inv, a2 = a[2] * inv, a3 = a[3] * inv;
        float a4 = a[4] * inv, a5 = a[5] * inv, a6 = a[6] * inv, a7 = a[7] * inv;
        asm("v_cvt_pk_bf16_f32 %0, %1, %2" : "=v"(o01) : "v"(a0), "v"(a1));
        asm("v_cvt_pk_bf16_f32 %0, %1, %2" : "=v"(o23) : "v"(a2), "v"(a3));
        asm("v_cvt_pk_bf16_f32 %0, %1, %2" : "=v"(o45) : "v"(a4), "v"(a5));
        asm("v_cvt_pk_bf16_f32 %0, %1, %2" : "=v"(o67) : "v"(a6), "v"(a7));
    }
    *(unsigned*)(zp + 4 * hi)         = o01;
    *(unsigned*)(zp + 4 * hi + 2)     = o23;
    *(unsigned*)(zp + 8 + 4 * hi)     = o45;
    *(unsigned*)(zp + 8 + 4 * hi + 2) = o67;
}

extern "C" void kernel_launch(void* const* d_in, const int* in_sizes, int n_in,
                              void* d_out, int out_size, void* d_ws, size_t ws_size,
                              hipStream_t stream)
{
    const float* resid = (const float*)d_in[0];
    const float* WQ = (const float*)d_in[1];
    const float* WK = (const float*)d_in[2];
    const float* WV = (const float*)d_in[3];
    const float* WO = (const float*)d_in[4];
    const float* bQ = (const float*)d_in[5];
    const float* bK = (const float*)d_in[6];
    const float* bV = (const float*)d_in[7];
    const float* bO = (const float*)d_in[8];
    const float* vK = (const float*)d_in[9];
    const float* vV = (const float*)d_in[10];
    float* out = (float*)d_out;
    float* ws  = (float*)d_ws;

    short* Zb   = (short*)ws;                       // 4096*256 bf16
    float* bqkv = ws + 3145728;                     // 768 f32
    short* Ab   = (short*)(ws + 3145728 + 768);     // 3,145,728 bf16
    short* Wqt  = Ab + 3145728;                     // 589,824
    short* WtO  = Wqt + 589824;                     // 196,608
    short* Qb2  = WtO + 196608;                     // 32*64*512  = 1,048,576
    short* Kb2  = Qb2 + 1048576;                    // 32*65*512  = 1,064,960
    short* Vt3  = Kb2 + 1064960;                    // 32*65*1024 = 2,129,920
    unsigned* PartA = (unsigned*)(Vt3 + 2129920);   // 10240*64*4 u32
    float*    PartL = (float*)(PartA + 2621440);    // 10240*32 f32

    const int conv_total = NRES + NWQ + NWO + 768 + 1024;
    conv_all<<<dim3((conv_total + 255) / 256), 256, 0, stream>>>(
        resid, WQ, WK, WV, WO, bQ, bK, bV, vK, vV,
        Ab, Wqt, WtO, bqkv, Kb2, Vt3);
    mm_qkv<<<dim3(12, 64), 256, 0, stream>>>(Ab, Wqt, bqkv, Qb2, Kb2, Vt3);
    attn_split<<<dim3(32 * NACT / 4), 256, 0, stream>>>(Qb2, Kb2, Vt3, PartA, PartL, Zb);
    attn_combine<<<dim3(392), 256, 0, stream>>>(PartA, PartL, Zb);
    mm_out<<<dim3(12, 64), 256, 0, stream>>>(Zb, WtO, bO, out);
}